// Round 10
// baseline (108.811 us; speedup 1.0000x reference)
//
#include <hip/hip_runtime.h>

#define PBLOCK 256        // pair_lvl block (unchanged structure)
#define FBLOCK 128        // final kernel block = 2 waves
// R22: each block processes TWO 1024-output tiles, software-pipelined.

typedef float v2f __attribute__((ext_vector_type(2)));

static __device__ __forceinline__ float ldz(const float* __restrict__ p, int i, int n) {
    return (i >= 0 && i < n) ? p[i] : 0.f;
}

// Phase barrier WITHOUT vmcnt drain.
#define BAR_LGKM() do { \
    asm volatile("s_waitcnt lgkmcnt(0)" ::: "memory"); \
    __builtin_amdgcn_s_barrier(); \
} while (0)

// Full drain barrier (boundary path only).
#define BAR_FULL() do { \
    asm volatile("s_waitcnt vmcnt(0) lgkmcnt(0)" ::: "memory"); \
    __builtin_amdgcn_s_barrier(); \
} while (0)

#define AS1C(p) ((const __attribute__((address_space(1))) unsigned int*)(p))
#define AS3(p)  ((__attribute__((address_space(3))) unsigned int*)(p))

// ---- scalar filter set (pair_lvl only) ----
struct QFilt {
    float b0e[5], b0o[5], a0e[5], a0o[5];
    float b1e[5], b1o[5], a1e[5], a1o[5];
};

static __device__ __forceinline__ QFilt load_qfilt(
    const float* __restrict__ g0a, const float* __restrict__ g0b,
    const float* __restrict__ g1a, const float* __restrict__ g1b) {
    const float S2 = 1.4142135623730951f;
    QFilt f;
#pragma unroll
    for (int i = 0; i < 5; ++i) {
        f.b0e[i] = g0b[8 - 2 * i]; f.b0o[i] = g0b[9 - 2 * i];
        f.a0e[i] = g0a[8 - 2 * i]; f.a0o[i] = g0a[9 - 2 * i];
        f.b1e[i] = S2 * g1b[8 - 2 * i]; f.b1o[i] = S2 * g1b[9 - 2 * i];
        f.a1e[i] = S2 * g1a[8 - 2 * i]; f.a1o[i] = S2 * g1a[9 - 2 * i];
    }
    return f;
}

// ---- packed filter set (final kernel) ----
struct QFiltP {
    v2f f01l[5], f23l[5], f01h[5], f23h[5];
};

static __device__ __forceinline__ QFiltP load_qfiltp(
    const float* __restrict__ g0a, const float* __restrict__ g0b,
    const float* __restrict__ g1a, const float* __restrict__ g1b) {
    const float S2 = 1.4142135623730951f;
    QFiltP f;
#pragma unroll
    for (int i = 0; i < 5; ++i) {
        float b0e = g0b[8 - 2 * i], b0o = g0b[9 - 2 * i];
        float a0e = g0a[8 - 2 * i], a0o = g0a[9 - 2 * i];
        float b1e = S2 * g1b[8 - 2 * i], b1o = S2 * g1b[9 - 2 * i];
        float a1e = S2 * g1a[8 - 2 * i], a1o = S2 * g1a[9 - 2 * i];
        f.f01l[i] = (v2f){b0e, a0e};
        f.f23l[i] = (v2f){b0o, a0o};
        f.f01h[i] = (v2f){b1e, a1e};
        f.f23h[i] = (v2f){b1o, a1o};
    }
    return f;
}

// Packed quad: out[4s..4s+3].
static __device__ __forceinline__ float4 quad_p(
    const float* base, int loOff, int riOff, int ioff, const QFiltP& f) {
    v2f y01 = (v2f){0.f, 0.f}, y23 = (v2f){0.f, 0.f};
#pragma unroll
    for (int i = 0; i < 5; ++i) {
        v2f lo2 = *reinterpret_cast<const v2f*>(base + loOff + 2 * i);
        v2f ri;
        ri.x = base[riOff + i];
        ri.y = base[riOff + ioff + i];
        y01 = __builtin_elementwise_fma(lo2, f.f01l[i], y01);
        y23 = __builtin_elementwise_fma(lo2, f.f23l[i], y23);
        y01 = __builtin_elementwise_fma(ri, f.f01h[i], y01);
        y23 = __builtin_elementwise_fma(ri, f.f23h[i], y23);
    }
    return make_float4(y01.x, y01.y, y23.x, y23.y);
}

// Interleaved-window quad (pair_lvl only, unchanged).
static __device__ __forceinline__ float4 quad_i(
    const float* __restrict__ lo_s, int lobase,
    const float* __restrict__ r_s, const float* __restrict__ i_s, int ribase,
    const QFilt& f) {
    float y0 = 0.f, y1 = 0.f, y2 = 0.f, y3 = 0.f;
#pragma unroll
    for (int i = 0; i < 5; ++i) {
        float ve = lo_s[lobase + 2 * i], vo = lo_s[lobase + 2 * i + 1];
        float vr = r_s[ribase + i], vi = i_s[ribase + i];
        y0 = fmaf(ve, f.b0e[i], y0); y2 = fmaf(ve, f.b0o[i], y2);
        y1 = fmaf(vo, f.a0e[i], y1); y3 = fmaf(vo, f.a0o[i], y3);
        y0 = fmaf(vr, f.b1e[i], y0); y2 = fmaf(vr, f.b1o[i], y2);
        y1 = fmaf(vi, f.a1e[i], y1); y3 = fmaf(vi, f.a1o[i], y3);
    }
    return make_float4(y0, y1, y2, y3);
}

static __device__ __forceinline__ float4 quad_d(
    const float* __restrict__ Ae, const float* __restrict__ Ao, int base,
    const float* __restrict__ r_s, const float* __restrict__ i_s, int ribase,
    const QFilt& f) {
    float y0 = 0.f, y1 = 0.f, y2 = 0.f, y3 = 0.f;
#pragma unroll
    for (int i = 0; i < 5; ++i) {
        float ve = Ae[base + i], vo = Ao[base + i];
        float vr = r_s[ribase + i], vi = i_s[ribase + i];
        y0 = fmaf(ve, f.b0e[i], y0); y2 = fmaf(ve, f.b0o[i], y2);
        y1 = fmaf(vo, f.a0e[i], y1); y3 = fmaf(vo, f.a0o[i], y3);
        y0 = fmaf(vr, f.b1e[i], y0); y2 = fmaf(vr, f.b1o[i], y2);
        y1 = fmaf(vi, f.a1e[i], y1); y3 = fmaf(vi, f.a1o[i], y3);
    }
    return make_float4(y0, y1, y2, y3);
}

// TWO fused coarse levels (R11 structure, unchanged — measured near floor).
__global__ void __launch_bounds__(PBLOCK) pair_lvl(
    const float* __restrict__ up,
    const float* __restrict__ ru, const float* __restrict__ iu,
    const float* __restrict__ rl, const float* __restrict__ il,
    float* __restrict__ out,
    const float* __restrict__ g0a, const float* __restrict__ g0b,
    const float* __restrict__ g1a, const float* __restrict__ g1b,
    int L)
{
    __shared__ __align__(16) float upw[272], ruw[140], iuw[140], rlw[264], ilw[264];
    __shared__ __align__(16) float Ae[260], Ao[260];
    int tid = threadIdx.x, bx = blockIdx.x, row = blockIdx.y;
    int lup = L >> 2, lu8 = L >> 3, lql = L >> 2;
    const float* uprow = up + (size_t)row * lup;
    const float* rurow = ru + (size_t)row * lu8;
    const float* iurow = iu + (size_t)row * lu8;
    const float* rlrow = rl + (size_t)row * lql;
    const float* ilrow = il + (size_t)row * lql;
    bool bnd = (bx == 0) || (bx == (int)gridDim.x - 1);
    int S = bx << 8;
    int sAu = (S >> 1) - 1;
    int gu = S - 8;
    int gru = (S >> 1) - 4;
    int grl = S - 4;

    for (int i = tid; i < 270; i += PBLOCK) {
        const float* src; float* dst; int k, gb, len;
        if (i < 68)       { src = uprow; dst = upw; k = i;       gb = gu + 4 * k;  len = lup; }
        else if (i < 103) { src = rurow; dst = ruw; k = i - 68;  gb = gru + 4 * k; len = lu8; }
        else if (i < 138) { src = iurow; dst = iuw; k = i - 103; gb = gru + 4 * k; len = lu8; }
        else if (i < 204) { src = rlrow; dst = rlw; k = i - 138; gb = grl + 4 * k; len = lql; }
        else              { src = ilrow; dst = ilw; k = i - 204; gb = grl + 4 * k; len = lql; }
        float4 v;
        if (!bnd) v = *reinterpret_cast<const float4*>(src + gb);
        else { v.x = ldz(src, gb, len); v.y = ldz(src, gb + 1, len);
               v.z = ldz(src, gb + 2, len); v.w = ldz(src, gb + 3, len); }
        *reinterpret_cast<float4*>(dst + 4 * k) = v;
    }
    __syncthreads();

    QFilt f = load_qfilt(g0a, g0b, g1a, g1b);
    if (tid < 130) {
        float4 q = quad_i(upw, 2 * tid + 2, ruw, iuw, tid + 1, f);
        if (bnd) {
            int sp = sAu + tid;
            if (sp < 0 || sp >= lu8) q = make_float4(0.f, 0.f, 0.f, 0.f);
        }
        Ae[2 * tid] = q.x; Ae[2 * tid + 1] = q.z;
        Ao[2 * tid] = q.y; Ao[2 * tid + 1] = q.w;
    }
    __syncthreads();

    float4 res = quad_d(Ae, Ao, tid, rlw, ilw, tid + 2, f);
    reinterpret_cast<float4*>(out + (size_t)row * L)[S + tid] = res;
}

// ---- R22 final kernel: two R21-tiles per block, straight-line pipelined.
// All VMEM issued at entry: st0(3/wave), et0(4), st1(3), et1(4).
// vmcnt(11) -> st0 done (et0+st1+et1 = 11 newer stay in flight).
// vmcnt(6)  -> st1 done (et1(4) + t0-stores(2) newer stay in flight).
// et0/et1 are register loads (compiler auto-inserts exact waits).
// LDS map (dwords): two staged buffers [0,1108) and [1108,2216); scratch
// shared between tiles (x3/x2/x1), reused after barriers.
#define O_X4 0      // x4  [148]  slots   0..36
#define O_R3 148    // yh3r [76]  slots  37..55   (i3 at +76)
#define O_I3 224    // yh3i [76]  slots  56..74
#define O_R2 300    // yh2r [140] slots  75..109  (i2 at +140)
#define O_I2 440    // yh2i [140] slots 110..144
#define O_R1 580    // yh1r [264] slots 145..210  (i1 at +264)
#define O_I1 844    // yh1i [264] slots 211..276
#define SBUF 1108   // staged-buffer stride (dwords)
#define O_X3 2216   // x3 values [280]
#define O_X2 2496   // x2 values [528]
#define O_X1 3024   // x1 quads  [1032]  (258 float4)
#define W_TOT 4056  // dwords = 16224 B
#define NSLOT 277

static __device__ __forceinline__ void slot_map(
    int i, int v0, int u0, int s0, int t4, int t8, int t16,
    const float* x4row, const float* r3row, const float* i3row,
    const float* r2row, const float* i2row,
    const float* r1row, const float* i1row,
    const float*& src, int& gb, int& len)
{
    if (i < 37)       { src = x4row; int k = i;       gb = 2 * v0 - 8 + 4 * k; len = t8;  }
    else if (i < 56)  { src = r3row; int k = i - 37;  gb = v0 - 4 + 4 * k;     len = t16; }
    else if (i < 75)  { src = i3row; int k = i - 56;  gb = v0 - 4 + 4 * k;     len = t16; }
    else if (i < 110) { src = r2row; int k = i - 75;  gb = u0 - 4 + 4 * k;     len = t8;  }
    else if (i < 145) { src = i2row; int k = i - 110; gb = u0 - 4 + 4 * k;     len = t8;  }
    else if (i < 211) { src = r1row; int k = i - 145; gb = s0 - 4 + 4 * k;     len = t4;  }
    else              { src = i1row; int k = i - 211; gb = s0 - 4 + 4 * k;     len = t4;  }
}

// Async stage of one tile: EXACTLY 3 global_load_lds per wave (wave-split
// slot ranges; 3rd instr partially predicated but exec != 0 on both waves,
// so per-wave vmcnt counts are uniform).
static __device__ __forceinline__ void stage_async_tile(
    float* W, int sb, int gtile, int wv, int lane,
    int t4, int t8, int t16,
    const float* x4row, const float* r3row, const float* i3row,
    const float* r2row, const float* i2row,
    const float* r1row, const float* i1row)
{
    int v0 = gtile << 6, u0 = gtile << 7, s0 = gtile << 8;
    int base_w = wv ? 139 : 0;
    int lim_w  = wv ? 277 : 139;
#pragma unroll
    for (int s = 0; s < 3; ++s) {
        int slot = base_w + 64 * s + lane;
        if (slot < lim_w) {
            const float* src; int gb, len;
            slot_map(slot, v0, u0, s0, t4, t8, t16,
                     x4row, r3row, i3row, r2row, i2row, r1row, i1row, src, gb, len);
            __builtin_amdgcn_global_load_lds(AS1C(src + gb), AS3(W + sb + 4 * slot), 16, 0, 0);
        }
    }
}

// Boundary-path register stage with zero clamping.
static __device__ __forceinline__ void stage_reg_tile(
    float* W, int sb, int gtile, int tid,
    int t4, int t8, int t16,
    const float* x4row, const float* r3row, const float* i3row,
    const float* r2row, const float* i2row,
    const float* r1row, const float* i1row)
{
    int v0 = gtile << 6, u0 = gtile << 7, s0 = gtile << 8;
#pragma unroll
    for (int it = 0; it < 3; ++it) {
        int i = tid + FBLOCK * it;
        if (i < NSLOT) {
            const float* src; int gb, len;
            slot_map(i, v0, u0, s0, t4, t8, t16,
                     x4row, r3row, i3row, r2row, i2row, r1row, i1row, src, gb, len);
            float4 v;
            v.x = ldz(src, gb, len);     v.y = ldz(src, gb + 1, len);
            v.z = ldz(src, gb + 2, len); v.w = ldz(src, gb + 3, len);
            *reinterpret_cast<float4*>(W + sb + 4 * i) = v;
        }
    }
}

// Phases A..D + store for one tile (R21 body, SB-relative staged reads).
template<bool BND>
static __device__ __forceinline__ void tile_phases(
    float* W, int SB, int gtile, int tid,
    int t4, int t8, int t16, int T_,
    const QFiltP& f, const float* g0r, const float* g1r,
    const float rA[6], const float iA[6],
    float* __restrict__ outrow)
{
    int s0 = gtile << 8, u0 = gtile << 7, v0 = gtile << 6;

    // ---- phase A: 69 x3-quads. quad v = v0-2+k. ----
    if (tid < 69) {
        int k = tid;
        float4 q = quad_p(W, SB + O_X4 + 2 * k, SB + O_R3 + k, 76, f);
        if (BND) {
            int v = v0 - 2 + k;
            if (v < 0 || v >= t16) q = make_float4(0.f, 0.f, 0.f, 0.f);
        }
        *reinterpret_cast<float4*>(W + O_X3 + 4 * k) = q;
    }
    BAR_LGKM();

    // ---- phase B: 132 x2-quads. ----
    {
        int k = tid;
        float4 q = quad_p(W, O_X3 + 2 * k, SB + O_R2 + k, 140, f);
        if (BND) {
            int u = u0 - 2 + k;
            if (u < 0 || u >= t8) q = make_float4(0.f, 0.f, 0.f, 0.f);
        }
        *reinterpret_cast<float4*>(W + O_X2 + 4 * k) = q;
        if (tid < 4) {
            int k2 = tid + FBLOCK;
            q = quad_p(W, O_X3 + 2 * k2, SB + O_R2 + k2, 140, f);
            if (BND) {
                int u = u0 - 2 + k2;
                if (u < 0 || u >= t8) q = make_float4(0.f, 0.f, 0.f, 0.f);
            }
            *reinterpret_cast<float4*>(W + O_X2 + 4 * k2) = q;
        }
    }
    BAR_LGKM();

    // ---- phase C: 258 x1-quads, 2 per thread in registers. ----
    float4 mq0, mq1;
    {
        int l = 2 * tid;
        mq0 = quad_p(W, O_X2 + 2 * l + 2, SB + O_R1 + l + 1, 264, f);
        mq1 = quad_p(W, O_X2 + 2 * l + 4, SB + O_R1 + l + 2, 264, f);
        if (BND) {
            int s = s0 - 1 + l;
            if (s < 0 || s >= t4)         mq0 = make_float4(0.f, 0.f, 0.f, 0.f);
            if (s + 1 < 0 || s + 1 >= t4) mq1 = make_float4(0.f, 0.f, 0.f, 0.f);
        }
        *reinterpret_cast<float4*>(W + O_X1 + 4 * l) = mq0;
        *reinterpret_cast<float4*>(W + O_X1 + 4 * (l + 1)) = mq1;
        if (tid < 2) {
            int l2 = 256 + tid;
            float4 q = quad_p(W, O_X2 + 2 * l2 + 2, SB + O_R1 + l2 + 1, 264, f);
            if (BND) {
                int s = s0 - 1 + l2;
                if (s < 0 || s >= t4) q = make_float4(0.f, 0.f, 0.f, 0.f);
            }
            *reinterpret_cast<float4*>(W + O_X1 + 4 * l2) = q;
        }
    }
    BAR_LGKM();

    // ---- phase D: 8 outputs. w[d] = x1[n0-4+8*tid+d]. ----
    float w[16];
    *reinterpret_cast<float4*>(&w[0])  = mq0;
    *reinterpret_cast<float4*>(&w[4])  = mq1;
    *reinterpret_cast<float4*>(&w[8])  = *reinterpret_cast<const float4*>(W + O_X1 + 4 * (2 * tid + 2));
    *reinterpret_cast<float4*>(&w[12]) = *reinterpret_cast<const float4*>(W + O_X1 + 4 * (2 * tid + 3));

    float o[8];
#pragma unroll
    for (int p = 0; p < 8; ++p) {
        float acc = 0.f;
#pragma unroll
        for (int j = 0; j < 7; ++j)
            acc = fmaf(g0r[j], w[p + 7 - j], acc);
#pragma unroll
        for (int j = 0; j < 5; ++j) {
            int e = p + 4 - j;
            float v = (e & 1) ? iA[e >> 1] : rA[e >> 1];
            acc = fmaf(g1r[j], v, acc);
        }
        o[p] = acc;
    }
    float4* op = reinterpret_cast<float4*>(outrow) + s0 + 2 * tid;
    op[0] = make_float4(o[0], o[1], o[2], o[3]);
    op[1] = make_float4(o[4], o[5], o[6], o[7]);
}

__global__ void __launch_bounds__(FBLOCK) final4_dt(
    const float* __restrict__ x4,                                 // T/8 per row
    const float* __restrict__ r3, const float* __restrict__ i3,   // T/16 per row
    const float* __restrict__ r2, const float* __restrict__ i2,   // T/8 per row
    const float* __restrict__ r1, const float* __restrict__ i1,   // T/4 per row
    const float* __restrict__ r0, const float* __restrict__ i0,   // T/2 per row
    float* __restrict__ out,                                      // T per row
    const float* __restrict__ g0a, const float* __restrict__ g0b,
    const float* __restrict__ g1a, const float* __restrict__ g1b,
    const float* __restrict__ g0o, const float* __restrict__ g1o,
    int T_)
{
    const float S2 = 1.4142135623730951f;
    __shared__ __align__(16) float W[W_TOT];

    int row = blockIdx.y, tid = threadIdx.x, bx = blockIdx.x;
    int lane = tid & 63, wv = tid >> 6;
    int t2 = T_ >> 1, t4 = T_ >> 2, t8 = T_ >> 3, t16 = T_ >> 4;
    int g0t = 2 * bx, g1t = 2 * bx + 1;
    const float* x4row = x4 + (size_t)row * t8;
    const float* r3row = r3 + (size_t)row * t16;
    const float* i3row = i3 + (size_t)row * t16;
    const float* r2row = r2 + (size_t)row * t8;
    const float* i2row = i2 + (size_t)row * t8;
    const float* r1row = r1 + (size_t)row * t4;
    const float* i1row = i1 + (size_t)row * t4;
    const float* r0row = r0 + (size_t)row * t2;
    const float* i0row = i0 + (size_t)row * t2;
    float* outrow = out + (size_t)row * T_;
    bool bnd = (bx == 0) || (bx == (int)gridDim.x - 1);

    float rA0[6], iA0[6], rA1[6], iA1[6];
    float g0r[7], g1r[5];

    if (!bnd) {
        // ---- issue ALL VMEM at entry, order pinned: st0, et0, st1, et1 ----
        stage_async_tile(W, 0, g0t, wv, lane, t4, t8, t16,
                         x4row, r3row, i3row, r2row, i2row, r1row, i1row);
        __builtin_amdgcn_sched_barrier(0);
        {   // et0: r0/i0 window of tile0 (4 VMEM/wave)
            int u0e = (g0t << 9) + 4 * tid - 1;
            float4 va = *reinterpret_cast<const float4*>(r0row + u0e);
            float2 va2 = *reinterpret_cast<const float2*>(r0row + u0e + 4);
            float4 vb = *reinterpret_cast<const float4*>(i0row + u0e);
            float2 vb2 = *reinterpret_cast<const float2*>(i0row + u0e + 4);
            rA0[0] = va.x; rA0[1] = va.y; rA0[2] = va.z; rA0[3] = va.w;
            rA0[4] = va2.x; rA0[5] = va2.y;
            iA0[0] = vb.x; iA0[1] = vb.y; iA0[2] = vb.z; iA0[3] = vb.w;
            iA0[4] = vb2.x; iA0[5] = vb2.y;
        }
        __builtin_amdgcn_sched_barrier(0);
        stage_async_tile(W, SBUF, g1t, wv, lane, t4, t8, t16,
                         x4row, r3row, i3row, r2row, i2row, r1row, i1row);
        __builtin_amdgcn_sched_barrier(0);
        {   // et1: r0/i0 window of tile1
            int u0e = (g1t << 9) + 4 * tid - 1;
            float4 va = *reinterpret_cast<const float4*>(r0row + u0e);
            float2 va2 = *reinterpret_cast<const float2*>(r0row + u0e + 4);
            float4 vb = *reinterpret_cast<const float4*>(i0row + u0e);
            float2 vb2 = *reinterpret_cast<const float2*>(i0row + u0e + 4);
            rA1[0] = va.x; rA1[1] = va.y; rA1[2] = va.z; rA1[3] = va.w;
            rA1[4] = va2.x; rA1[5] = va2.y;
            iA1[0] = vb.x; iA1[1] = vb.y; iA1[2] = vb.z; iA1[3] = vb.w;
            iA1[4] = vb2.x; iA1[5] = vb2.y;
        }
        __builtin_amdgcn_sched_barrier(0);

        // filters (uniform -> SMEM; even if VMEM, counted waits only over-drain)
        QFiltP f = load_qfiltp(g0a, g0b, g1a, g1b);
#pragma unroll
        for (int j = 0; j < 7; ++j) g0r[j] = g0o[j];
#pragma unroll
        for (int j = 0; j < 5; ++j) g1r[j] = S2 * g1o[j];

        // st0 done: 11 newer VMEM (et0 4 + st1 3 + et1 4) may stay in flight.
        asm volatile("s_waitcnt vmcnt(11) lgkmcnt(0)" ::: "memory");
        __builtin_amdgcn_s_barrier();

        tile_phases<false>(W, 0, g0t, tid, t4, t8, t16, T_, f, g0r, g1r,
                           rA0, iA0, outrow);

        // st1 done: newer = et1(4) + tile0 stores(2) -> vmcnt(6).
        asm volatile("s_waitcnt vmcnt(6) lgkmcnt(0)" ::: "memory");
        __builtin_amdgcn_s_barrier();

        tile_phases<false>(W, SBUF, g1t, tid, t4, t8, t16, T_, f, g0r, g1r,
                           rA1, iA1, outrow);
    } else {
        // ---- boundary path (2 blocks per row): simple, full drains ----
        QFiltP f = load_qfiltp(g0a, g0b, g1a, g1b);
#pragma unroll
        for (int j = 0; j < 7; ++j) g0r[j] = g0o[j];
#pragma unroll
        for (int j = 0; j < 5; ++j) g1r[j] = S2 * g1o[j];

        // tile 0 of this block
        stage_reg_tile(W, 0, g0t, tid, t4, t8, t16,
                       x4row, r3row, i3row, r2row, i2row, r1row, i1row);
        {
            int u0e = (g0t << 9) + 4 * tid - 1;
#pragma unroll
            for (int e = 0; e < 6; ++e) {
                rA0[e] = ldz(r0row, u0e + e, t2);
                iA0[e] = ldz(i0row, u0e + e, t2);
            }
        }
        BAR_FULL();
        tile_phases<true>(W, 0, g0t, tid, t4, t8, t16, T_, f, g0r, g1r,
                          rA0, iA0, outrow);
        BAR_FULL();

        // tile 1
        stage_reg_tile(W, SBUF, g1t, tid, t4, t8, t16,
                       x4row, r3row, i3row, r2row, i2row, r1row, i1row);
        {
            int u0e = (g1t << 9) + 4 * tid - 1;
#pragma unroll
            for (int e = 0; e < 6; ++e) {
                rA1[e] = ldz(r0row, u0e + e, t2);
                iA1[e] = ldz(i0row, u0e + e, t2);
            }
        }
        BAR_FULL();
        tile_phases<true>(W, SBUF, g1t, tid, t4, t8, t16, T_, f, g0r, g1r,
                          rA1, iA1, outrow);
    }
}

extern "C" void kernel_launch(void* const* d_in, const int* in_sizes, int n_in,
                              void* d_out, int out_size, void* d_ws, size_t ws_size,
                              hipStream_t stream)
{
    const float* yl = (const float*)d_in[0];
    const float* yhr[8]; const float* yhi[8];
    for (int j = 0; j < 8; ++j) {
        yhr[j] = (const float*)d_in[1 + 2 * j];
        yhi[j] = (const float*)d_in[2 + 2 * j];
    }
    const float* g0o = (const float*)d_in[17];
    const float* g1o = (const float*)d_in[18];
    const float* g0a = (const float*)d_in[19];
    const float* g0b = (const float*)d_in[20];
    const float* g1a = (const float*)d_in[21];
    const float* g1b = (const float*)d_in[22];

    const int BC = 32 * 4;
    const int T_ = 262144;

    // Scratch: final reads x4 while writing the FULL d_out, so x4/x6 live in ws.
    float* x4buf = (float*)d_ws;
    float* x6buf = (float*)((char*)d_ws + ((size_t)32 << 20));

    // K76: yl + yh7 + yh6 -> x6 (L = 8192)
    {
        dim3 grid(8192 / 1024, BC);
        pair_lvl<<<grid, PBLOCK, 0, stream>>>(
            yl, yhr[7], yhi[7], yhr[6], yhi[6], x6buf,
            g0a, g0b, g1a, g1b, 8192);
    }
    // K54: x6 + yh5 + yh4 -> x4 (L = 32768)
    {
        dim3 grid(32768 / 1024, BC);
        pair_lvl<<<grid, PBLOCK, 0, stream>>>(
            x6buf, yhr[5], yhi[5], yhr[4], yhi[4], x4buf,
            g0a, g0b, g1a, g1b, 32768);
    }
    // final4_dt: x4 + yh3..yh0 -> out. 2 tiles/block, straight-line pipeline.
    dim3 grid(T_ / 2048, BC);
    final4_dt<<<grid, FBLOCK, 0, stream>>>(
        x4buf, yhr[3], yhi[3], yhr[2], yhi[2], yhr[1], yhi[1],
        yhr[0], yhi[0], (float*)d_out,
        g0a, g0b, g1a, g1b, g0o, g1o, T_);
}

// Round 11
// 104.368 us; speedup vs baseline: 1.0426x; 1.0426x over previous
//
#include <hip/hip_runtime.h>

#define PBLOCK 256        // pair_lvl block (unchanged structure)
#define FBLOCK 128        // final kernel block = 2 waves
#define FT 1024           // 8 outputs/thread (2 x1-quads/thread in C)

typedef float v2f __attribute__((ext_vector_type(2)));

static __device__ __forceinline__ float ldz(const float* __restrict__ p, int i, int n) {
    return (i >= 0 && i < n) ? p[i] : 0.f;
}

// Phase barrier WITHOUT vmcnt drain: LDS visibility across waves needs
// lgkmcnt only. Keeps the rA/iA epilogue global loads in flight across
// phases A..C.
#define BAR_LGKM() do { \
    asm volatile("s_waitcnt lgkmcnt(0)" ::: "memory"); \
    __builtin_amdgcn_s_barrier(); \
} while (0)

// Full drain barrier (stage): global_load_lds completions are counted by
// vmcnt, so LDS visibility of the staged data needs vmcnt(0) here.
#define BAR_FULL() do { \
    asm volatile("s_waitcnt vmcnt(0) lgkmcnt(0)" ::: "memory"); \
    __builtin_amdgcn_s_barrier(); \
} while (0)

#define AS1C(p) ((const __attribute__((address_space(1))) unsigned int*)(p))
#define AS3(p)  ((__attribute__((address_space(3))) unsigned int*)(p))

// ---- scalar filter set (pair_lvl only) ----
struct QFilt {
    float b0e[5], b0o[5], a0e[5], a0o[5];
    float b1e[5], b1o[5], a1e[5], a1o[5];
};

static __device__ __forceinline__ QFilt load_qfilt(
    const float* __restrict__ g0a, const float* __restrict__ g0b,
    const float* __restrict__ g1a, const float* __restrict__ g1b) {
    const float S2 = 1.4142135623730951f;
    QFilt f;
#pragma unroll
    for (int i = 0; i < 5; ++i) {
        f.b0e[i] = g0b[8 - 2 * i]; f.b0o[i] = g0b[9 - 2 * i];
        f.a0e[i] = g0a[8 - 2 * i]; f.a0o[i] = g0a[9 - 2 * i];
        f.b1e[i] = S2 * g1b[8 - 2 * i]; f.b1o[i] = S2 * g1b[9 - 2 * i];
        f.a1e[i] = S2 * g1a[8 - 2 * i]; f.a1o[i] = S2 * g1a[9 - 2 * i];
    }
    return f;
}

// ---- packed filter set (final kernel) ----
struct QFiltP {
    v2f f01l[5], f23l[5], f01h[5], f23h[5];
};

static __device__ __forceinline__ QFiltP load_qfiltp(
    const float* __restrict__ g0a, const float* __restrict__ g0b,
    const float* __restrict__ g1a, const float* __restrict__ g1b) {
    const float S2 = 1.4142135623730951f;
    QFiltP f;
#pragma unroll
    for (int i = 0; i < 5; ++i) {
        float b0e = g0b[8 - 2 * i], b0o = g0b[9 - 2 * i];
        float a0e = g0a[8 - 2 * i], a0o = g0a[9 - 2 * i];
        float b1e = S2 * g1b[8 - 2 * i], b1o = S2 * g1b[9 - 2 * i];
        float a1e = S2 * g1a[8 - 2 * i], a1o = S2 * g1a[9 - 2 * i];
        f.f01l[i] = (v2f){b0e, a0e};
        f.f23l[i] = (v2f){b0o, a0o};
        f.f01h[i] = (v2f){b1e, a1e};
        f.f23h[i] = (v2f){b1o, a1o};
    }
    return f;
}

// Packed quad: out[4s..4s+3]. lo window as float2 loads (ds_read_b64),
// r/i pair as two b32 (mergeable to ds_read2_b32, ioff<=255).
static __device__ __forceinline__ float4 quad_p(
    const float* base, int loOff, int riOff, int ioff, const QFiltP& f) {
    v2f y01 = (v2f){0.f, 0.f}, y23 = (v2f){0.f, 0.f};
#pragma unroll
    for (int i = 0; i < 5; ++i) {
        v2f lo2 = *reinterpret_cast<const v2f*>(base + loOff + 2 * i);
        v2f ri;
        ri.x = base[riOff + i];
        ri.y = base[riOff + ioff + i];
        y01 = __builtin_elementwise_fma(lo2, f.f01l[i], y01);
        y23 = __builtin_elementwise_fma(lo2, f.f23l[i], y23);
        y01 = __builtin_elementwise_fma(ri, f.f01h[i], y01);
        y23 = __builtin_elementwise_fma(ri, f.f23h[i], y23);
    }
    return make_float4(y01.x, y01.y, y23.x, y23.y);
}

// Interleaved-window quad (pair_lvl only, unchanged).
static __device__ __forceinline__ float4 quad_i(
    const float* __restrict__ lo_s, int lobase,
    const float* __restrict__ r_s, const float* __restrict__ i_s, int ribase,
    const QFilt& f) {
    float y0 = 0.f, y1 = 0.f, y2 = 0.f, y3 = 0.f;
#pragma unroll
    for (int i = 0; i < 5; ++i) {
        float ve = lo_s[lobase + 2 * i], vo = lo_s[lobase + 2 * i + 1];
        float vr = r_s[ribase + i], vi = i_s[ribase + i];
        y0 = fmaf(ve, f.b0e[i], y0); y2 = fmaf(ve, f.b0o[i], y2);
        y1 = fmaf(vo, f.a0e[i], y1); y3 = fmaf(vo, f.a0o[i], y3);
        y0 = fmaf(vr, f.b1e[i], y0); y2 = fmaf(vr, f.b1o[i], y2);
        y1 = fmaf(vi, f.a1e[i], y1); y3 = fmaf(vi, f.a1o[i], y3);
    }
    return make_float4(y0, y1, y2, y3);
}

static __device__ __forceinline__ float4 quad_d(
    const float* __restrict__ Ae, const float* __restrict__ Ao, int base,
    const float* __restrict__ r_s, const float* __restrict__ i_s, int ribase,
    const QFilt& f) {
    float y0 = 0.f, y1 = 0.f, y2 = 0.f, y3 = 0.f;
#pragma unroll
    for (int i = 0; i < 5; ++i) {
        float ve = Ae[base + i], vo = Ao[base + i];
        float vr = r_s[ribase + i], vi = i_s[ribase + i];
        y0 = fmaf(ve, f.b0e[i], y0); y2 = fmaf(ve, f.b0o[i], y2);
        y1 = fmaf(vo, f.a0e[i], y1); y3 = fmaf(vo, f.a0o[i], y3);
        y0 = fmaf(vr, f.b1e[i], y0); y2 = fmaf(vr, f.b1o[i], y2);
        y1 = fmaf(vi, f.a1e[i], y1); y3 = fmaf(vi, f.a1o[i], y3);
    }
    return make_float4(y0, y1, y2, y3);
}

// Wave-neighbor pull: lane l gets v from lane l+1 (wraps at 63; wrap value
// is overwritten from the LDS patch by the caller).
static __device__ __forceinline__ float4 shfl_down4(float4 v) {
    float4 r;
    r.x = __shfl_down(v.x, 1, 64);
    r.y = __shfl_down(v.y, 1, 64);
    r.z = __shfl_down(v.z, 1, 64);
    r.w = __shfl_down(v.w, 1, 64);
    return r;
}

// TWO fused coarse levels (R11 structure, unchanged — measured near floor).
__global__ void __launch_bounds__(PBLOCK) pair_lvl(
    const float* __restrict__ up,
    const float* __restrict__ ru, const float* __restrict__ iu,
    const float* __restrict__ rl, const float* __restrict__ il,
    float* __restrict__ out,
    const float* __restrict__ g0a, const float* __restrict__ g0b,
    const float* __restrict__ g1a, const float* __restrict__ g1b,
    int L)
{
    __shared__ __align__(16) float upw[272], ruw[140], iuw[140], rlw[264], ilw[264];
    __shared__ __align__(16) float Ae[260], Ao[260];
    int tid = threadIdx.x, bx = blockIdx.x, row = blockIdx.y;
    int lup = L >> 2, lu8 = L >> 3, lql = L >> 2;
    const float* uprow = up + (size_t)row * lup;
    const float* rurow = ru + (size_t)row * lu8;
    const float* iurow = iu + (size_t)row * lu8;
    const float* rlrow = rl + (size_t)row * lql;
    const float* ilrow = il + (size_t)row * lql;
    bool bnd = (bx == 0) || (bx == (int)gridDim.x - 1);
    int S = bx << 8;
    int sAu = (S >> 1) - 1;
    int gu = S - 8;
    int gru = (S >> 1) - 4;
    int grl = S - 4;

    for (int i = tid; i < 270; i += PBLOCK) {
        const float* src; float* dst; int k, gb, len;
        if (i < 68)       { src = uprow; dst = upw; k = i;       gb = gu + 4 * k;  len = lup; }
        else if (i < 103) { src = rurow; dst = ruw; k = i - 68;  gb = gru + 4 * k; len = lu8; }
        else if (i < 138) { src = iurow; dst = iuw; k = i - 103; gb = gru + 4 * k; len = lu8; }
        else if (i < 204) { src = rlrow; dst = rlw; k = i - 138; gb = grl + 4 * k; len = lql; }
        else              { src = ilrow; dst = ilw; k = i - 204; gb = grl + 4 * k; len = lql; }
        float4 v;
        if (!bnd) v = *reinterpret_cast<const float4*>(src + gb);
        else { v.x = ldz(src, gb, len); v.y = ldz(src, gb + 1, len);
               v.z = ldz(src, gb + 2, len); v.w = ldz(src, gb + 3, len); }
        *reinterpret_cast<float4*>(dst + 4 * k) = v;
    }
    __syncthreads();

    QFilt f = load_qfilt(g0a, g0b, g1a, g1b);
    if (tid < 130) {
        float4 q = quad_i(upw, 2 * tid + 2, ruw, iuw, tid + 1, f);
        if (bnd) {
            int sp = sAu + tid;
            if (sp < 0 || sp >= lu8) q = make_float4(0.f, 0.f, 0.f, 0.f);
        }
        Ae[2 * tid] = q.x; Ae[2 * tid + 1] = q.z;
        Ao[2 * tid] = q.y; Ao[2 * tid + 1] = q.w;
    }
    __syncthreads();

    float4 res = quad_d(Ae, Ao, tid, rlw, ilw, tid + 2, f);
    reinterpret_cast<float4*>(out + (size_t)row * L)[S + tid] = res;
}

// ---- R23 final kernel: R21 structure with the x1q LDS array DELETED.
// Thread t's phase-D neighbor quads (2t+2, 2t+3 = thread t+1's register
// pair) come via __shfl_down (ds_bpermute); only the two wave-seam cases go
// through a 16-dword LDS patch:
//   patch[0..7]   <- tid 64's (mq0,mq1)   (read by tid 63)
//   patch[8..15]  <- extra quads 256,257  (computed by tid 0,1; read by 127)
// LDS: 12288 -> ~7.9 KB, so the 16-workgroup/CU (32-wave) cap becomes the
// occupancy limit (was 13 blocks via LDS). Everything else identical to R21.
#define O_X4 0      // x4  [148]  slots   0..36
#define O_R3 148    // yh3r [76]  slots  37..55   (i3 at +76)
#define O_I3 224    // yh3i [76]  slots  56..74
#define O_R2 300    // yh2r [140] slots  75..109  (i2 at +140)
#define O_I2 440    // yh2i [140] slots 110..144
#define O_R1 580    // yh1r [264] slots 145..210  (i1 at +264)
#define O_I1 844    // yh1i [264] slots 211..276
#define O_X3 1108   // x3 values [280]
#define O_X2 1388   // x2 values [528]
#define O_PT 1916   // patch [16]
#define W_TOT 1932  // dwords = 7728 B
#define NSLOT 277

static __device__ __forceinline__ void slot_map(
    int i, int v0, int u0, int s0, int t4, int t8, int t16,
    const float* x4row, const float* r3row, const float* i3row,
    const float* r2row, const float* i2row,
    const float* r1row, const float* i1row,
    const float*& src, int& gb, int& len)
{
    if (i < 37)       { src = x4row; int k = i;       gb = 2 * v0 - 8 + 4 * k; len = t8;  }
    else if (i < 56)  { src = r3row; int k = i - 37;  gb = v0 - 4 + 4 * k;     len = t16; }
    else if (i < 75)  { src = i3row; int k = i - 56;  gb = v0 - 4 + 4 * k;     len = t16; }
    else if (i < 110) { src = r2row; int k = i - 75;  gb = u0 - 4 + 4 * k;     len = t8;  }
    else if (i < 145) { src = i2row; int k = i - 110; gb = u0 - 4 + 4 * k;     len = t8;  }
    else if (i < 211) { src = r1row; int k = i - 145; gb = s0 - 4 + 4 * k;     len = t4;  }
    else              { src = i1row; int k = i - 211; gb = s0 - 4 + 4 * k;     len = t4;  }
}

__global__ void __launch_bounds__(FBLOCK) final4_async(
    const float* __restrict__ x4,                                 // T/8 per row
    const float* __restrict__ r3, const float* __restrict__ i3,   // T/16 per row
    const float* __restrict__ r2, const float* __restrict__ i2,   // T/8 per row
    const float* __restrict__ r1, const float* __restrict__ i1,   // T/4 per row
    const float* __restrict__ r0, const float* __restrict__ i0,   // T/2 per row
    float* __restrict__ out,                                      // T per row
    const float* __restrict__ g0a, const float* __restrict__ g0b,
    const float* __restrict__ g1a, const float* __restrict__ g1b,
    const float* __restrict__ g0o, const float* __restrict__ g1o,
    int T_)
{
    const float S2 = 1.4142135623730951f;
    __shared__ __align__(16) float W[W_TOT];

    int row = blockIdx.y, tid = threadIdx.x, bx = blockIdx.x;
    int t2 = T_ >> 1, t4 = T_ >> 2, t8 = T_ >> 3, t16 = T_ >> 4;
    int s0 = bx << 8, u0 = bx << 7, v0 = bx << 6, h0 = bx << 9;
    const float* x4row = x4 + (size_t)row * t8;
    const float* r3row = r3 + (size_t)row * t16;
    const float* i3row = i3 + (size_t)row * t16;
    const float* r2row = r2 + (size_t)row * t8;
    const float* i2row = i2 + (size_t)row * t8;
    const float* r1row = r1 + (size_t)row * t4;
    const float* i1row = i1 + (size_t)row * t4;
    const float* r0row = r0 + (size_t)row * t2;
    const float* i0row = i0 + (size_t)row * t2;
    bool bnd = (bx == 0) || (bx == (int)gridDim.x - 1);

    // ---- stage: 277 float4 slots, direct HBM -> LDS (wave-linear dest) ----
    if (!bnd) {
#pragma unroll
        for (int it = 0; it < 2; ++it) {
            int i = tid + FBLOCK * it;
            const float* src; int gb, len;
            slot_map(i, v0, u0, s0, t4, t8, t16,
                     x4row, r3row, i3row, r2row, i2row, r1row, i1row, src, gb, len);
            __builtin_amdgcn_global_load_lds(AS1C(src + gb), AS3(W + 4 * i), 16, 0, 0);
        }
        if (tid < NSLOT - 2 * FBLOCK) {
            int i = tid + 2 * FBLOCK;
            const float* src; int gb, len;
            slot_map(i, v0, u0, s0, t4, t8, t16,
                     x4row, r3row, i3row, r2row, i2row, r1row, i1row, src, gb, len);
            __builtin_amdgcn_global_load_lds(AS1C(src + gb), AS3(W + 4 * i), 16, 0, 0);
        }
    } else {
#pragma unroll
        for (int it = 0; it < 3; ++it) {
            int i = tid + FBLOCK * it;
            if (i < NSLOT) {
                const float* src; int gb, len;
                slot_map(i, v0, u0, s0, t4, t8, t16,
                         x4row, r3row, i3row, r2row, i2row, r1row, i1row, src, gb, len);
                float4 v;
                v.x = ldz(src, gb, len);     v.y = ldz(src, gb + 1, len);
                v.z = ldz(src, gb + 2, len); v.w = ldz(src, gb + 3, len);
                *reinterpret_cast<float4*>(W + 4 * i) = v;
            }
        }
    }
    BAR_FULL();   // staged LDS data visible; nothing else in flight yet

    // ---- epilogue loads issued NOW: stay in flight under phases A..C ----
    // rA[e] = r0[h0 + 4*tid - 1 + e], e = 0..5 (8 outputs need 6-wide window)
    float rA[6], iA[6];
    {
        int u0e = h0 + 4 * tid - 1;
        if (!bnd) {
            float4 va = *reinterpret_cast<const float4*>(r0row + u0e);
            float2 va2 = *reinterpret_cast<const float2*>(r0row + u0e + 4);
            float4 vb = *reinterpret_cast<const float4*>(i0row + u0e);
            float2 vb2 = *reinterpret_cast<const float2*>(i0row + u0e + 4);
            rA[0] = va.x; rA[1] = va.y; rA[2] = va.z; rA[3] = va.w;
            rA[4] = va2.x; rA[5] = va2.y;
            iA[0] = vb.x; iA[1] = vb.y; iA[2] = vb.z; iA[3] = vb.w;
            iA[4] = vb2.x; iA[5] = vb2.y;
        } else {
#pragma unroll
            for (int e = 0; e < 6; ++e) {
                rA[e] = ldz(r0row, u0e + e, t2);
                iA[e] = ldz(i0row, u0e + e, t2);
            }
        }
    }

    QFiltP f = load_qfiltp(g0a, g0b, g1a, g1b);
    float g0r[7], g1r[5];
#pragma unroll
    for (int j = 0; j < 7; ++j) g0r[j] = g0o[j];
#pragma unroll
    for (int j = 0; j < 5; ++j) g1r[j] = S2 * g1o[j];

    // ---- phase A: 69 x3-quads. quad v = v0-2+k. ----
    if (tid < 69) {
        int k = tid;
        float4 q = quad_p(W, O_X4 + 2 * k, O_R3 + k, 76, f);
        if (bnd) {
            int v = v0 - 2 + k;
            if (v < 0 || v >= t16) q = make_float4(0.f, 0.f, 0.f, 0.f);
        }
        *reinterpret_cast<float4*>(W + O_X3 + 4 * k) = q;
    }
    BAR_LGKM();

    // ---- phase B: 132 x2-quads. quad u = u0-2+k; k = tid and tid+128 (<4). ----
    {
        int k = tid;
        float4 q = quad_p(W, O_X3 + 2 * k, O_R2 + k, 140, f);
        if (bnd) {
            int u = u0 - 2 + k;
            if (u < 0 || u >= t8) q = make_float4(0.f, 0.f, 0.f, 0.f);
        }
        *reinterpret_cast<float4*>(W + O_X2 + 4 * k) = q;
        if (tid < 4) {
            int k2 = tid + FBLOCK;
            q = quad_p(W, O_X3 + 2 * k2, O_R2 + k2, 140, f);
            if (bnd) {
                int u = u0 - 2 + k2;
                if (u < 0 || u >= t8) q = make_float4(0.f, 0.f, 0.f, 0.f);
            }
            *reinterpret_cast<float4*>(W + O_X2 + 4 * k2) = q;
        }
    }
    BAR_LGKM();

    // ---- phase C: 258 x1-quads, 2 per thread (l = 2t, 2t+1; s = s0-1+l),
    // KEPT IN REGISTERS. Only the wave-seam values go to the LDS patch:
    // tid 64 -> patch[0..7]; extras 256,257 (tid 0,1) -> patch[8..15]. ----
    float4 mq0, mq1;
    {
        int l = 2 * tid;
        mq0 = quad_p(W, O_X2 + 2 * l + 2, O_R1 + l + 1, 264, f);
        mq1 = quad_p(W, O_X2 + 2 * l + 4, O_R1 + l + 2, 264, f);
        if (bnd) {
            int s = s0 - 1 + l;
            if (s < 0 || s >= t4)         mq0 = make_float4(0.f, 0.f, 0.f, 0.f);
            if (s + 1 < 0 || s + 1 >= t4) mq1 = make_float4(0.f, 0.f, 0.f, 0.f);
        }
        if (tid == 64) {
            *reinterpret_cast<float4*>(W + O_PT)     = mq0;
            *reinterpret_cast<float4*>(W + O_PT + 4) = mq1;
        }
        if (tid < 2) {
            int l2 = 256 + tid;
            float4 q = quad_p(W, O_X2 + 2 * l2 + 2, O_R1 + l2 + 1, 264, f);
            if (bnd) {
                int s = s0 - 1 + l2;
                if (s < 0 || s >= t4) q = make_float4(0.f, 0.f, 0.f, 0.f);
            }
            *reinterpret_cast<float4*>(W + O_PT + 8 + 4 * tid) = q;
        }
    }
    // Wave-local neighbor exchange (no barrier needed for these):
    float4 nq0 = shfl_down4(mq0);
    float4 nq1 = shfl_down4(mq1);
    BAR_LGKM();   // patch visibility across waves

    // ---- phase D: 8 outputs. w[d] = x1[n0-4+8*tid+d] (quads 2t..2t+3). ----
    if (tid == 63) {   // needs tid 64's pair (cross-wave)
        nq0 = *reinterpret_cast<const float4*>(W + O_PT);
        nq1 = *reinterpret_cast<const float4*>(W + O_PT + 4);
    }
    if (tid == 127) {  // needs extra quads 256, 257
        nq0 = *reinterpret_cast<const float4*>(W + O_PT + 8);
        nq1 = *reinterpret_cast<const float4*>(W + O_PT + 12);
    }

    float w[16];
    *reinterpret_cast<float4*>(&w[0])  = mq0;
    *reinterpret_cast<float4*>(&w[4])  = mq1;
    *reinterpret_cast<float4*>(&w[8])  = nq0;
    *reinterpret_cast<float4*>(&w[12]) = nq1;

    float o[8];
#pragma unroll
    for (int p = 0; p < 8; ++p) {
        float acc = 0.f;
#pragma unroll
        for (int j = 0; j < 7; ++j)          // x1[n+3-j] -> w[p+7-j]
            acc = fmaf(g0r[j], w[p + 7 - j], acc);
#pragma unroll
        for (int j = 0; j < 5; ++j) {        // hi0[n+2-j] -> e = p+4-j
            int e = p + 4 - j;
            float v = (e & 1) ? iA[e >> 1] : rA[e >> 1];
            acc = fmaf(g1r[j], v, acc);
        }
        o[p] = acc;
    }
    float4* op = reinterpret_cast<float4*>(out + (size_t)row * T_) + s0 + 2 * tid;
    op[0] = make_float4(o[0], o[1], o[2], o[3]);
    op[1] = make_float4(o[4], o[5], o[6], o[7]);
}

extern "C" void kernel_launch(void* const* d_in, const int* in_sizes, int n_in,
                              void* d_out, int out_size, void* d_ws, size_t ws_size,
                              hipStream_t stream)
{
    const float* yl = (const float*)d_in[0];
    const float* yhr[8]; const float* yhi[8];
    for (int j = 0; j < 8; ++j) {
        yhr[j] = (const float*)d_in[1 + 2 * j];
        yhi[j] = (const float*)d_in[2 + 2 * j];
    }
    const float* g0o = (const float*)d_in[17];
    const float* g1o = (const float*)d_in[18];
    const float* g0a = (const float*)d_in[19];
    const float* g0b = (const float*)d_in[20];
    const float* g1a = (const float*)d_in[21];
    const float* g1b = (const float*)d_in[22];

    const int BC = 32 * 4;
    const int T_ = 262144;

    // Scratch: final reads x4 while writing the FULL d_out, so x4/x6 live in ws.
    float* x4buf = (float*)d_ws;
    float* x6buf = (float*)((char*)d_ws + ((size_t)32 << 20));

    // K76: yl + yh7 + yh6 -> x6 (L = 8192)
    {
        dim3 grid(8192 / 1024, BC);
        pair_lvl<<<grid, PBLOCK, 0, stream>>>(
            yl, yhr[7], yhi[7], yhr[6], yhi[6], x6buf,
            g0a, g0b, g1a, g1b, 8192);
    }
    // K54: x6 + yh5 + yh4 -> x4 (L = 32768)
    {
        dim3 grid(32768 / 1024, BC);
        pair_lvl<<<grid, PBLOCK, 0, stream>>>(
            x6buf, yhr[5], yhi[5], yhr[4], yhi[4], x4buf,
            g0a, g0b, g1a, g1b, 32768);
    }
    // final4_async: x4 + yh3..yh0 -> out. FT=1024, 128T, 8 outputs/thread,
    // x1 neighbor exchange via shuffle (LDS ~7.9 KB -> 16 blocks/CU cap).
    dim3 grid(T_ / FT, BC);
    final4_async<<<grid, FBLOCK, 0, stream>>>(
        x4buf, yhr[3], yhi[3], yhr[2], yhi[2], yhr[1], yhi[1],
        yhr[0], yhi[0], (float*)d_out,
        g0a, g0b, g1a, g1b, g0o, g1o, T_);
}

// Round 12
// 103.985 us; speedup vs baseline: 1.0464x; 1.0037x over previous
//
#include <hip/hip_runtime.h>

#define PBLOCK 256        // pair_lvl block (unchanged structure)
#define FBLOCK 128        // final kernel block = 2 waves
#define FT 1024           // 8 outputs/thread (2 x1-quads/thread in C)

typedef float v2f __attribute__((ext_vector_type(2)));

static __device__ __forceinline__ float ldz(const float* __restrict__ p, int i, int n) {
    return (i >= 0 && i < n) ? p[i] : 0.f;
}

// Phase barrier WITHOUT vmcnt drain: LDS visibility across waves needs
// lgkmcnt only. Keeps the hoisted global loads in flight across phases.
#define BAR_LGKM() do { \
    asm volatile("s_waitcnt lgkmcnt(0)" ::: "memory"); \
    __builtin_amdgcn_s_barrier(); \
} while (0)

// Full drain barrier (stage): global_load_lds completions are counted by
// vmcnt, so LDS visibility of the staged data needs vmcnt(0) here.
#define BAR_FULL() do { \
    asm volatile("s_waitcnt vmcnt(0) lgkmcnt(0)" ::: "memory"); \
    __builtin_amdgcn_s_barrier(); \
} while (0)

#define AS1C(p) ((const __attribute__((address_space(1))) unsigned int*)(p))
#define AS3(p)  ((__attribute__((address_space(3))) unsigned int*)(p))

// ---- scalar filter set (pair_lvl only) ----
struct QFilt {
    float b0e[5], b0o[5], a0e[5], a0o[5];
    float b1e[5], b1o[5], a1e[5], a1o[5];
};

static __device__ __forceinline__ QFilt load_qfilt(
    const float* __restrict__ g0a, const float* __restrict__ g0b,
    const float* __restrict__ g1a, const float* __restrict__ g1b) {
    const float S2 = 1.4142135623730951f;
    QFilt f;
#pragma unroll
    for (int i = 0; i < 5; ++i) {
        f.b0e[i] = g0b[8 - 2 * i]; f.b0o[i] = g0b[9 - 2 * i];
        f.a0e[i] = g0a[8 - 2 * i]; f.a0o[i] = g0a[9 - 2 * i];
        f.b1e[i] = S2 * g1b[8 - 2 * i]; f.b1o[i] = S2 * g1b[9 - 2 * i];
        f.a1e[i] = S2 * g1a[8 - 2 * i]; f.a1o[i] = S2 * g1a[9 - 2 * i];
    }
    return f;
}

// ---- packed filter set (final kernel) ----
struct QFiltP {
    v2f f01l[5], f23l[5], f01h[5], f23h[5];
};

static __device__ __forceinline__ QFiltP load_qfiltp(
    const float* __restrict__ g0a, const float* __restrict__ g0b,
    const float* __restrict__ g1a, const float* __restrict__ g1b) {
    const float S2 = 1.4142135623730951f;
    QFiltP f;
#pragma unroll
    for (int i = 0; i < 5; ++i) {
        float b0e = g0b[8 - 2 * i], b0o = g0b[9 - 2 * i];
        float a0e = g0a[8 - 2 * i], a0o = g0a[9 - 2 * i];
        float b1e = S2 * g1b[8 - 2 * i], b1o = S2 * g1b[9 - 2 * i];
        float a1e = S2 * g1a[8 - 2 * i], a1o = S2 * g1a[9 - 2 * i];
        f.f01l[i] = (v2f){b0e, a0e};
        f.f23l[i] = (v2f){b0o, a0o};
        f.f01h[i] = (v2f){b1e, a1e};
        f.f23h[i] = (v2f){b1o, a1o};
    }
    return f;
}

// Packed quad, r/i from LDS (phases A/B): lo window as float2 loads,
// r/i pair at constant dword distance ioff (ds_read2_b32).
static __device__ __forceinline__ float4 quad_p(
    const float* base, int loOff, int riOff, int ioff, const QFiltP& f) {
    v2f y01 = (v2f){0.f, 0.f}, y23 = (v2f){0.f, 0.f};
#pragma unroll
    for (int i = 0; i < 5; ++i) {
        v2f lo2 = *reinterpret_cast<const v2f*>(base + loOff + 2 * i);
        v2f ri;
        ri.x = base[riOff + i];
        ri.y = base[riOff + ioff + i];
        y01 = __builtin_elementwise_fma(lo2, f.f01l[i], y01);
        y23 = __builtin_elementwise_fma(lo2, f.f23l[i], y23);
        y01 = __builtin_elementwise_fma(ri, f.f01h[i], y01);
        y23 = __builtin_elementwise_fma(ri, f.f23h[i], y23);
    }
    return make_float4(y01.x, y01.y, y23.x, y23.y);
}

// R24: packed quad with r/i from REGISTER windows (phase C). rr/ii are
// 8-wide per-thread windows; off is a compile-time literal at each call
// site, so rr[off+i]/ii[off+i] are static register accesses after unroll.
static __device__ __forceinline__ float4 quad_r(
    const float* base, int loOff,
    const float* rr, const float* ii, int off, const QFiltP& f) {
    v2f y01 = (v2f){0.f, 0.f}, y23 = (v2f){0.f, 0.f};
#pragma unroll
    for (int i = 0; i < 5; ++i) {
        v2f lo2 = *reinterpret_cast<const v2f*>(base + loOff + 2 * i);
        v2f ri;
        ri.x = rr[off + i];
        ri.y = ii[off + i];
        y01 = __builtin_elementwise_fma(lo2, f.f01l[i], y01);
        y23 = __builtin_elementwise_fma(lo2, f.f23l[i], y23);
        y01 = __builtin_elementwise_fma(ri, f.f01h[i], y01);
        y23 = __builtin_elementwise_fma(ri, f.f23h[i], y23);
    }
    return make_float4(y01.x, y01.y, y23.x, y23.y);
}

// Interleaved-window quad (pair_lvl only, unchanged).
static __device__ __forceinline__ float4 quad_i(
    const float* __restrict__ lo_s, int lobase,
    const float* __restrict__ r_s, const float* __restrict__ i_s, int ribase,
    const QFilt& f) {
    float y0 = 0.f, y1 = 0.f, y2 = 0.f, y3 = 0.f;
#pragma unroll
    for (int i = 0; i < 5; ++i) {
        float ve = lo_s[lobase + 2 * i], vo = lo_s[lobase + 2 * i + 1];
        float vr = r_s[ribase + i], vi = i_s[ribase + i];
        y0 = fmaf(ve, f.b0e[i], y0); y2 = fmaf(ve, f.b0o[i], y2);
        y1 = fmaf(vo, f.a0e[i], y1); y3 = fmaf(vo, f.a0o[i], y3);
        y0 = fmaf(vr, f.b1e[i], y0); y2 = fmaf(vr, f.b1o[i], y2);
        y1 = fmaf(vi, f.a1e[i], y1); y3 = fmaf(vi, f.a1o[i], y3);
    }
    return make_float4(y0, y1, y2, y3);
}

static __device__ __forceinline__ float4 quad_d(
    const float* __restrict__ Ae, const float* __restrict__ Ao, int base,
    const float* __restrict__ r_s, const float* __restrict__ i_s, int ribase,
    const QFilt& f) {
    float y0 = 0.f, y1 = 0.f, y2 = 0.f, y3 = 0.f;
#pragma unroll
    for (int i = 0; i < 5; ++i) {
        float ve = Ae[base + i], vo = Ao[base + i];
        float vr = r_s[ribase + i], vi = i_s[ribase + i];
        y0 = fmaf(ve, f.b0e[i], y0); y2 = fmaf(ve, f.b0o[i], y2);
        y1 = fmaf(vo, f.a0e[i], y1); y3 = fmaf(vo, f.a0o[i], y3);
        y0 = fmaf(vr, f.b1e[i], y0); y2 = fmaf(vr, f.b1o[i], y2);
        y1 = fmaf(vi, f.a1e[i], y1); y3 = fmaf(vi, f.a1o[i], y3);
    }
    return make_float4(y0, y1, y2, y3);
}

// Wave-neighbor pull: lane l gets v from lane l+1 (wraps at 63; wrap value
// is overwritten from the LDS patch / recomputed by the caller).
static __device__ __forceinline__ float4 shfl_down4(float4 v) {
    float4 r;
    r.x = __shfl_down(v.x, 1, 64);
    r.y = __shfl_down(v.y, 1, 64);
    r.z = __shfl_down(v.z, 1, 64);
    r.w = __shfl_down(v.w, 1, 64);
    return r;
}

// TWO fused coarse levels (R11 structure, unchanged — measured near floor).
__global__ void __launch_bounds__(PBLOCK) pair_lvl(
    const float* __restrict__ up,
    const float* __restrict__ ru, const float* __restrict__ iu,
    const float* __restrict__ rl, const float* __restrict__ il,
    float* __restrict__ out,
    const float* __restrict__ g0a, const float* __restrict__ g0b,
    const float* __restrict__ g1a, const float* __restrict__ g1b,
    int L)
{
    __shared__ __align__(16) float upw[272], ruw[140], iuw[140], rlw[264], ilw[264];
    __shared__ __align__(16) float Ae[260], Ao[260];
    int tid = threadIdx.x, bx = blockIdx.x, row = blockIdx.y;
    int lup = L >> 2, lu8 = L >> 3, lql = L >> 2;
    const float* uprow = up + (size_t)row * lup;
    const float* rurow = ru + (size_t)row * lu8;
    const float* iurow = iu + (size_t)row * lu8;
    const float* rlrow = rl + (size_t)row * lql;
    const float* ilrow = il + (size_t)row * lql;
    bool bnd = (bx == 0) || (bx == (int)gridDim.x - 1);
    int S = bx << 8;
    int sAu = (S >> 1) - 1;
    int gu = S - 8;
    int gru = (S >> 1) - 4;
    int grl = S - 4;

    for (int i = tid; i < 270; i += PBLOCK) {
        const float* src; float* dst; int k, gb, len;
        if (i < 68)       { src = uprow; dst = upw; k = i;       gb = gu + 4 * k;  len = lup; }
        else if (i < 103) { src = rurow; dst = ruw; k = i - 68;  gb = gru + 4 * k; len = lu8; }
        else if (i < 138) { src = iurow; dst = iuw; k = i - 103; gb = gru + 4 * k; len = lu8; }
        else if (i < 204) { src = rlrow; dst = rlw; k = i - 138; gb = grl + 4 * k; len = lql; }
        else              { src = ilrow; dst = ilw; k = i - 204; gb = grl + 4 * k; len = lql; }
        float4 v;
        if (!bnd) v = *reinterpret_cast<const float4*>(src + gb);
        else { v.x = ldz(src, gb, len); v.y = ldz(src, gb + 1, len);
               v.z = ldz(src, gb + 2, len); v.w = ldz(src, gb + 3, len); }
        *reinterpret_cast<float4*>(dst + 4 * k) = v;
    }
    __syncthreads();

    QFilt f = load_qfilt(g0a, g0b, g1a, g1b);
    if (tid < 130) {
        float4 q = quad_i(upw, 2 * tid + 2, ruw, iuw, tid + 1, f);
        if (bnd) {
            int sp = sAu + tid;
            if (sp < 0 || sp >= lu8) q = make_float4(0.f, 0.f, 0.f, 0.f);
        }
        Ae[2 * tid] = q.x; Ae[2 * tid + 1] = q.z;
        Ao[2 * tid] = q.y; Ao[2 * tid + 1] = q.w;
    }
    __syncthreads();

    float4 res = quad_d(Ae, Ao, tid, rlw, ilw, tid + 2, f);
    reinterpret_cast<float4*>(out + (size_t)row * L)[S + tid] = res;
}

// ---- R24 final kernel: R23 structure with yh1 (r1/i1) REMOVED from LDS.
// Each thread loads its 8-wide r1/i1 windows into registers (4 VMEM, issued
// after the stage barrier -> in flight under phases A..B, consumed in C).
// Phase C's 10 LDS r/i reads per thread vanish; stage drops 277->145 slots;
// LDS 8.2 -> 5.6 KB. The 8-wide window also lets tid 127 compute the two
// extra seam quads (256,257) itself (off=2,3) -> no tid0/1 extra path.
// rr[j] = r1[s0 + 2*tid - 3 + j], j=0..7; quad l=2t+c uses off=c: rr[c+i].
#define O_X4 0      // x4  [148]  slots   0..36
#define O_R3 148    // yh3r [76]  slots  37..55   (i3 at +76)
#define O_I3 224    // yh3i [76]  slots  56..74
#define O_R2 300    // yh2r [140] slots  75..109  (i2 at +140)
#define O_I2 440    // yh2i [140] slots 110..144
#define O_X3 580    // x3 values [280]
#define O_X2 860    // x2 values [528]
#define O_PT 1388   // patch [8]: tid 64's (mq0,mq1) for tid 63
#define W_TOT 1396  // dwords = 5584 B
#define NSLOT 145

static __device__ __forceinline__ void slot_map(
    int i, int v0, int u0, int t8, int t16,
    const float* x4row, const float* r3row, const float* i3row,
    const float* r2row, const float* i2row,
    const float*& src, int& gb, int& len)
{
    if (i < 37)       { src = x4row; int k = i;       gb = 2 * v0 - 8 + 4 * k; len = t8;  }
    else if (i < 56)  { src = r3row; int k = i - 37;  gb = v0 - 4 + 4 * k;     len = t16; }
    else if (i < 75)  { src = i3row; int k = i - 56;  gb = v0 - 4 + 4 * k;     len = t16; }
    else if (i < 110) { src = r2row; int k = i - 75;  gb = u0 - 4 + 4 * k;     len = t8;  }
    else              { src = i2row; int k = i - 110; gb = u0 - 4 + 4 * k;     len = t8;  }
}

__global__ void __launch_bounds__(FBLOCK) final4_async(
    const float* __restrict__ x4,                                 // T/8 per row
    const float* __restrict__ r3, const float* __restrict__ i3,   // T/16 per row
    const float* __restrict__ r2, const float* __restrict__ i2,   // T/8 per row
    const float* __restrict__ r1, const float* __restrict__ i1,   // T/4 per row
    const float* __restrict__ r0, const float* __restrict__ i0,   // T/2 per row
    float* __restrict__ out,                                      // T per row
    const float* __restrict__ g0a, const float* __restrict__ g0b,
    const float* __restrict__ g1a, const float* __restrict__ g1b,
    const float* __restrict__ g0o, const float* __restrict__ g1o,
    int T_)
{
    const float S2 = 1.4142135623730951f;
    __shared__ __align__(16) float W[W_TOT];

    int row = blockIdx.y, tid = threadIdx.x, bx = blockIdx.x;
    int t2 = T_ >> 1, t4 = T_ >> 2, t8 = T_ >> 3, t16 = T_ >> 4;
    int s0 = bx << 8, u0 = bx << 7, v0 = bx << 6, h0 = bx << 9;
    const float* x4row = x4 + (size_t)row * t8;
    const float* r3row = r3 + (size_t)row * t16;
    const float* i3row = i3 + (size_t)row * t16;
    const float* r2row = r2 + (size_t)row * t8;
    const float* i2row = i2 + (size_t)row * t8;
    const float* r1row = r1 + (size_t)row * t4;
    const float* i1row = i1 + (size_t)row * t4;
    const float* r0row = r0 + (size_t)row * t2;
    const float* i0row = i0 + (size_t)row * t2;
    bool bnd = (bx == 0) || (bx == (int)gridDim.x - 1);

    // ---- stage: 145 float4 slots, direct HBM -> LDS (wave-linear dest) ----
    if (!bnd) {
        {
            int i = tid;
            const float* src; int gb, len;
            slot_map(i, v0, u0, t8, t16, x4row, r3row, i3row, r2row, i2row,
                     src, gb, len);
            __builtin_amdgcn_global_load_lds(AS1C(src + gb), AS3(W + 4 * i), 16, 0, 0);
        }
        if (tid < NSLOT - FBLOCK) {   // 17 tail slots
            int i = tid + FBLOCK;
            const float* src; int gb, len;
            slot_map(i, v0, u0, t8, t16, x4row, r3row, i3row, r2row, i2row,
                     src, gb, len);
            __builtin_amdgcn_global_load_lds(AS1C(src + gb), AS3(W + 4 * i), 16, 0, 0);
        }
    } else {
#pragma unroll
        for (int it = 0; it < 2; ++it) {
            int i = tid + FBLOCK * it;
            if (i < NSLOT) {
                const float* src; int gb, len;
                slot_map(i, v0, u0, t8, t16, x4row, r3row, i3row, r2row, i2row,
                         src, gb, len);
                float4 v;
                v.x = ldz(src, gb, len);     v.y = ldz(src, gb + 1, len);
                v.z = ldz(src, gb + 2, len); v.w = ldz(src, gb + 3, len);
                *reinterpret_cast<float4*>(W + 4 * i) = v;
            }
        }
    }
    BAR_FULL();   // staged LDS data visible; nothing else in flight yet

    // ---- hoisted register loads, in flight under phases A..B/C ----
    // epilogue: rA[e] = r0[h0 + 4*tid - 1 + e], e = 0..5
    float rA[6], iA[6];
    {
        int u0e = h0 + 4 * tid - 1;
        if (!bnd) {
            float4 va = *reinterpret_cast<const float4*>(r0row + u0e);
            float2 va2 = *reinterpret_cast<const float2*>(r0row + u0e + 4);
            float4 vb = *reinterpret_cast<const float4*>(i0row + u0e);
            float2 vb2 = *reinterpret_cast<const float2*>(i0row + u0e + 4);
            rA[0] = va.x; rA[1] = va.y; rA[2] = va.z; rA[3] = va.w;
            rA[4] = va2.x; rA[5] = va2.y;
            iA[0] = vb.x; iA[1] = vb.y; iA[2] = vb.z; iA[3] = vb.w;
            iA[4] = vb2.x; iA[5] = vb2.y;
        } else {
#pragma unroll
            for (int e = 0; e < 6; ++e) {
                rA[e] = ldz(r0row, u0e + e, t2);
                iA[e] = ldz(i0row, u0e + e, t2);
            }
        }
    }
    // yh1 windows: rr[j] = r1[s0 + 2*tid - 3 + j], j = 0..7 (ii from i1)
    float rr[8], ii[8];
    {
        int g1 = s0 + 2 * tid - 3;
        if (!bnd) {
            float4 a0 = *reinterpret_cast<const float4*>(r1row + g1);
            float4 a1 = *reinterpret_cast<const float4*>(r1row + g1 + 4);
            float4 b0 = *reinterpret_cast<const float4*>(i1row + g1);
            float4 b1 = *reinterpret_cast<const float4*>(i1row + g1 + 4);
            rr[0] = a0.x; rr[1] = a0.y; rr[2] = a0.z; rr[3] = a0.w;
            rr[4] = a1.x; rr[5] = a1.y; rr[6] = a1.z; rr[7] = a1.w;
            ii[0] = b0.x; ii[1] = b0.y; ii[2] = b0.z; ii[3] = b0.w;
            ii[4] = b1.x; ii[5] = b1.y; ii[6] = b1.z; ii[7] = b1.w;
        } else {
#pragma unroll
            for (int j = 0; j < 8; ++j) {
                rr[j] = ldz(r1row, g1 + j, t4);
                ii[j] = ldz(i1row, g1 + j, t4);
            }
        }
    }

    QFiltP f = load_qfiltp(g0a, g0b, g1a, g1b);
    float g0r[7], g1r[5];
#pragma unroll
    for (int j = 0; j < 7; ++j) g0r[j] = g0o[j];
#pragma unroll
    for (int j = 0; j < 5; ++j) g1r[j] = S2 * g1o[j];

    // ---- phase A: 69 x3-quads. quad v = v0-2+k. ----
    if (tid < 69) {
        int k = tid;
        float4 q = quad_p(W, O_X4 + 2 * k, O_R3 + k, 76, f);
        if (bnd) {
            int v = v0 - 2 + k;
            if (v < 0 || v >= t16) q = make_float4(0.f, 0.f, 0.f, 0.f);
        }
        *reinterpret_cast<float4*>(W + O_X3 + 4 * k) = q;
    }
    BAR_LGKM();

    // ---- phase B: 132 x2-quads. quad u = u0-2+k; k = tid and tid+128 (<4). ----
    {
        int k = tid;
        float4 q = quad_p(W, O_X3 + 2 * k, O_R2 + k, 140, f);
        if (bnd) {
            int u = u0 - 2 + k;
            if (u < 0 || u >= t8) q = make_float4(0.f, 0.f, 0.f, 0.f);
        }
        *reinterpret_cast<float4*>(W + O_X2 + 4 * k) = q;
        if (tid < 4) {
            int k2 = tid + FBLOCK;
            q = quad_p(W, O_X3 + 2 * k2, O_R2 + k2, 140, f);
            if (bnd) {
                int u = u0 - 2 + k2;
                if (u < 0 || u >= t8) q = make_float4(0.f, 0.f, 0.f, 0.f);
            }
            *reinterpret_cast<float4*>(W + O_X2 + 4 * k2) = q;
        }
    }
    BAR_LGKM();

    // ---- phase C: x1 quads 2t, 2t+1 per thread, r/i from REGISTERS. ----
    float4 mq0, mq1;
    {
        int l = 2 * tid;
        mq0 = quad_r(W, O_X2 + 2 * l + 2, rr, ii, 0, f);
        mq1 = quad_r(W, O_X2 + 2 * l + 4, rr, ii, 1, f);
        if (bnd) {
            int s = s0 - 1 + l;
            if (s < 0 || s >= t4)         mq0 = make_float4(0.f, 0.f, 0.f, 0.f);
            if (s + 1 < 0 || s + 1 >= t4) mq1 = make_float4(0.f, 0.f, 0.f, 0.f);
        }
        if (tid == 64) {   // seam: tid 63 needs this pair (cross-wave)
            *reinterpret_cast<float4*>(W + O_PT)     = mq0;
            *reinterpret_cast<float4*>(W + O_PT + 4) = mq1;
        }
    }
    // Wave-local neighbor exchange:
    float4 nq0 = shfl_down4(mq0);
    float4 nq1 = shfl_down4(mq1);
    BAR_LGKM();   // patch visibility across waves

    // Seam fixups:
    if (tid == 63) {   // needs tid 64's pair (cross-wave patch)
        nq0 = *reinterpret_cast<const float4*>(W + O_PT);
        nq1 = *reinterpret_cast<const float4*>(W + O_PT + 4);
    }
    if (tid == 127) {  // computes extra quads 256,257 itself (off=2,3)
        float4 q0 = quad_r(W, O_X2 + 2 * 256 + 2, rr, ii, 2, f);
        float4 q1 = quad_r(W, O_X2 + 2 * 257 + 2, rr, ii, 3, f);
        if (bnd) {
            int s = s0 - 1 + 256;
            if (s < 0 || s >= t4)         q0 = make_float4(0.f, 0.f, 0.f, 0.f);
            if (s + 1 < 0 || s + 1 >= t4) q1 = make_float4(0.f, 0.f, 0.f, 0.f);
        }
        nq0 = q0; nq1 = q1;
    }

    // ---- phase D: 8 outputs. w[d] = x1[n0-4+8*tid+d] (quads 2t..2t+3). ----
    float w[16];
    *reinterpret_cast<float4*>(&w[0])  = mq0;
    *reinterpret_cast<float4*>(&w[4])  = mq1;
    *reinterpret_cast<float4*>(&w[8])  = nq0;
    *reinterpret_cast<float4*>(&w[12]) = nq1;

    float o[8];
#pragma unroll
    for (int p = 0; p < 8; ++p) {
        float acc = 0.f;
#pragma unroll
        for (int j = 0; j < 7; ++j)          // x1[n+3-j] -> w[p+7-j]
            acc = fmaf(g0r[j], w[p + 7 - j], acc);
#pragma unroll
        for (int j = 0; j < 5; ++j) {        // hi0[n+2-j] -> e = p+4-j
            int e = p + 4 - j;
            float v = (e & 1) ? iA[e >> 1] : rA[e >> 1];
            acc = fmaf(g1r[j], v, acc);
        }
        o[p] = acc;
    }
    float4* op = reinterpret_cast<float4*>(out + (size_t)row * T_) + s0 + 2 * tid;
    op[0] = make_float4(o[0], o[1], o[2], o[3]);
    op[1] = make_float4(o[4], o[5], o[6], o[7]);
}

extern "C" void kernel_launch(void* const* d_in, const int* in_sizes, int n_in,
                              void* d_out, int out_size, void* d_ws, size_t ws_size,
                              hipStream_t stream)
{
    const float* yl = (const float*)d_in[0];
    const float* yhr[8]; const float* yhi[8];
    for (int j = 0; j < 8; ++j) {
        yhr[j] = (const float*)d_in[1 + 2 * j];
        yhi[j] = (const float*)d_in[2 + 2 * j];
    }
    const float* g0o = (const float*)d_in[17];
    const float* g1o = (const float*)d_in[18];
    const float* g0a = (const float*)d_in[19];
    const float* g0b = (const float*)d_in[20];
    const float* g1a = (const float*)d_in[21];
    const float* g1b = (const float*)d_in[22];

    const int BC = 32 * 4;
    const int T_ = 262144;

    // Scratch: final reads x4 while writing the FULL d_out, so x4/x6 live in ws.
    float* x4buf = (float*)d_ws;
    float* x6buf = (float*)((char*)d_ws + ((size_t)32 << 20));

    // K76: yl + yh7 + yh6 -> x6 (L = 8192)
    {
        dim3 grid(8192 / 1024, BC);
        pair_lvl<<<grid, PBLOCK, 0, stream>>>(
            yl, yhr[7], yhi[7], yhr[6], yhi[6], x6buf,
            g0a, g0b, g1a, g1b, 8192);
    }
    // K54: x6 + yh5 + yh4 -> x4 (L = 32768)
    {
        dim3 grid(32768 / 1024, BC);
        pair_lvl<<<grid, PBLOCK, 0, stream>>>(
            x6buf, yhr[5], yhi[5], yhr[4], yhi[4], x4buf,
            g0a, g0b, g1a, g1b, 32768);
    }
    // final4_async: x4 + yh3..yh0 -> out. FT=1024, 128T, 8 outputs/thread,
    // yh1 register-resident, x1 neighbor exchange via shuffle.
    dim3 grid(T_ / FT, BC);
    final4_async<<<grid, FBLOCK, 0, stream>>>(
        x4buf, yhr[3], yhi[3], yhr[2], yhi[2], yhr[1], yhi[1],
        yhr[0], yhi[0], (float*)d_out,
        g0a, g0b, g1a, g1b, g0o, g1o, T_);
}

// Round 13
// 103.854 us; speedup vs baseline: 1.0477x; 1.0013x over previous
//
#include <hip/hip_runtime.h>

#define PBLOCK 256        // pair_lvl block (unchanged structure)
#define FBLOCK 128        // final kernel block = 2 waves
#define FT 1024           // 8 outputs/thread (2 x1-quads/thread in C)

typedef float v2f __attribute__((ext_vector_type(2)));

static __device__ __forceinline__ float ldz(const float* __restrict__ p, int i, int n) {
    return (i >= 0 && i < n) ? p[i] : 0.f;
}

// Phase barrier WITHOUT vmcnt drain: LDS visibility across waves needs
// lgkmcnt only. Keeps the hoisted global loads in flight across phases.
#define BAR_LGKM() do { \
    asm volatile("s_waitcnt lgkmcnt(0)" ::: "memory"); \
    __builtin_amdgcn_s_barrier(); \
} while (0)

// Full drain barrier (boundary path): global_load_lds completions are
// counted by vmcnt, so LDS visibility of staged data needs vmcnt(0) there.
#define BAR_FULL() do { \
    asm volatile("s_waitcnt vmcnt(0) lgkmcnt(0)" ::: "memory"); \
    __builtin_amdgcn_s_barrier(); \
} while (0)

#define AS1C(p) ((const __attribute__((address_space(1))) unsigned int*)(p))
#define AS3(p)  ((__attribute__((address_space(3))) unsigned int*)(p))

// ---- scalar filter set (pair_lvl only) ----
struct QFilt {
    float b0e[5], b0o[5], a0e[5], a0o[5];
    float b1e[5], b1o[5], a1e[5], a1o[5];
};

static __device__ __forceinline__ QFilt load_qfilt(
    const float* __restrict__ g0a, const float* __restrict__ g0b,
    const float* __restrict__ g1a, const float* __restrict__ g1b) {
    const float S2 = 1.4142135623730951f;
    QFilt f;
#pragma unroll
    for (int i = 0; i < 5; ++i) {
        f.b0e[i] = g0b[8 - 2 * i]; f.b0o[i] = g0b[9 - 2 * i];
        f.a0e[i] = g0a[8 - 2 * i]; f.a0o[i] = g0a[9 - 2 * i];
        f.b1e[i] = S2 * g1b[8 - 2 * i]; f.b1o[i] = S2 * g1b[9 - 2 * i];
        f.a1e[i] = S2 * g1a[8 - 2 * i]; f.a1o[i] = S2 * g1a[9 - 2 * i];
    }
    return f;
}

// ---- packed filter set (final kernel) ----
struct QFiltP {
    v2f f01l[5], f23l[5], f01h[5], f23h[5];
};

static __device__ __forceinline__ QFiltP load_qfiltp(
    const float* __restrict__ g0a, const float* __restrict__ g0b,
    const float* __restrict__ g1a, const float* __restrict__ g1b) {
    const float S2 = 1.4142135623730951f;
    QFiltP f;
#pragma unroll
    for (int i = 0; i < 5; ++i) {
        float b0e = g0b[8 - 2 * i], b0o = g0b[9 - 2 * i];
        float a0e = g0a[8 - 2 * i], a0o = g0a[9 - 2 * i];
        float b1e = S2 * g1b[8 - 2 * i], b1o = S2 * g1b[9 - 2 * i];
        float a1e = S2 * g1a[8 - 2 * i], a1o = S2 * g1a[9 - 2 * i];
        f.f01l[i] = (v2f){b0e, a0e};
        f.f23l[i] = (v2f){b0o, a0o};
        f.f01h[i] = (v2f){b1e, a1e};
        f.f23h[i] = (v2f){b1o, a1o};
    }
    return f;
}

// Packed quad, r/i from LDS (phases A/B): lo window as float2 loads,
// r/i pair at constant dword distance ioff (ds_read2_b32).
static __device__ __forceinline__ float4 quad_p(
    const float* base, int loOff, int riOff, int ioff, const QFiltP& f) {
    v2f y01 = (v2f){0.f, 0.f}, y23 = (v2f){0.f, 0.f};
#pragma unroll
    for (int i = 0; i < 5; ++i) {
        v2f lo2 = *reinterpret_cast<const v2f*>(base + loOff + 2 * i);
        v2f ri;
        ri.x = base[riOff + i];
        ri.y = base[riOff + ioff + i];
        y01 = __builtin_elementwise_fma(lo2, f.f01l[i], y01);
        y23 = __builtin_elementwise_fma(lo2, f.f23l[i], y23);
        y01 = __builtin_elementwise_fma(ri, f.f01h[i], y01);
        y23 = __builtin_elementwise_fma(ri, f.f23h[i], y23);
    }
    return make_float4(y01.x, y01.y, y23.x, y23.y);
}

// Packed quad with r/i from REGISTER windows (phase C). off is a
// compile-time literal at each call site -> static register accesses.
static __device__ __forceinline__ float4 quad_r(
    const float* base, int loOff,
    const float* rr, const float* ii, int off, const QFiltP& f) {
    v2f y01 = (v2f){0.f, 0.f}, y23 = (v2f){0.f, 0.f};
#pragma unroll
    for (int i = 0; i < 5; ++i) {
        v2f lo2 = *reinterpret_cast<const v2f*>(base + loOff + 2 * i);
        v2f ri;
        ri.x = rr[off + i];
        ri.y = ii[off + i];
        y01 = __builtin_elementwise_fma(lo2, f.f01l[i], y01);
        y23 = __builtin_elementwise_fma(lo2, f.f23l[i], y23);
        y01 = __builtin_elementwise_fma(ri, f.f01h[i], y01);
        y23 = __builtin_elementwise_fma(ri, f.f23h[i], y23);
    }
    return make_float4(y01.x, y01.y, y23.x, y23.y);
}

// Interleaved-window quad (pair_lvl only, unchanged).
static __device__ __forceinline__ float4 quad_i(
    const float* __restrict__ lo_s, int lobase,
    const float* __restrict__ r_s, const float* __restrict__ i_s, int ribase,
    const QFilt& f) {
    float y0 = 0.f, y1 = 0.f, y2 = 0.f, y3 = 0.f;
#pragma unroll
    for (int i = 0; i < 5; ++i) {
        float ve = lo_s[lobase + 2 * i], vo = lo_s[lobase + 2 * i + 1];
        float vr = r_s[ribase + i], vi = i_s[ribase + i];
        y0 = fmaf(ve, f.b0e[i], y0); y2 = fmaf(ve, f.b0o[i], y2);
        y1 = fmaf(vo, f.a0e[i], y1); y3 = fmaf(vo, f.a0o[i], y3);
        y0 = fmaf(vr, f.b1e[i], y0); y2 = fmaf(vr, f.b1o[i], y2);
        y1 = fmaf(vi, f.a1e[i], y1); y3 = fmaf(vi, f.a1o[i], y3);
    }
    return make_float4(y0, y1, y2, y3);
}

static __device__ __forceinline__ float4 quad_d(
    const float* __restrict__ Ae, const float* __restrict__ Ao, int base,
    const float* __restrict__ r_s, const float* __restrict__ i_s, int ribase,
    const QFilt& f) {
    float y0 = 0.f, y1 = 0.f, y2 = 0.f, y3 = 0.f;
#pragma unroll
    for (int i = 0; i < 5; ++i) {
        float ve = Ae[base + i], vo = Ao[base + i];
        float vr = r_s[ribase + i], vi = i_s[ribase + i];
        y0 = fmaf(ve, f.b0e[i], y0); y2 = fmaf(ve, f.b0o[i], y2);
        y1 = fmaf(vo, f.a0e[i], y1); y3 = fmaf(vo, f.a0o[i], y3);
        y0 = fmaf(vr, f.b1e[i], y0); y2 = fmaf(vr, f.b1o[i], y2);
        y1 = fmaf(vi, f.a1e[i], y1); y3 = fmaf(vi, f.a1o[i], y3);
    }
    return make_float4(y0, y1, y2, y3);
}

// Wave-neighbor pull: lane l gets v from lane l+1 (wraps at 63; wrap value
// is overwritten from the LDS patch / recomputed by the caller).
static __device__ __forceinline__ float4 shfl_down4(float4 v) {
    float4 r;
    r.x = __shfl_down(v.x, 1, 64);
    r.y = __shfl_down(v.y, 1, 64);
    r.z = __shfl_down(v.z, 1, 64);
    r.w = __shfl_down(v.w, 1, 64);
    return r;
}

// TWO fused coarse levels (R11 structure, unchanged — measured near floor).
__global__ void __launch_bounds__(PBLOCK) pair_lvl(
    const float* __restrict__ up,
    const float* __restrict__ ru, const float* __restrict__ iu,
    const float* __restrict__ rl, const float* __restrict__ il,
    float* __restrict__ out,
    const float* __restrict__ g0a, const float* __restrict__ g0b,
    const float* __restrict__ g1a, const float* __restrict__ g1b,
    int L)
{
    __shared__ __align__(16) float upw[272], ruw[140], iuw[140], rlw[264], ilw[264];
    __shared__ __align__(16) float Ae[260], Ao[260];
    int tid = threadIdx.x, bx = blockIdx.x, row = blockIdx.y;
    int lup = L >> 2, lu8 = L >> 3, lql = L >> 2;
    const float* uprow = up + (size_t)row * lup;
    const float* rurow = ru + (size_t)row * lu8;
    const float* iurow = iu + (size_t)row * lu8;
    const float* rlrow = rl + (size_t)row * lql;
    const float* ilrow = il + (size_t)row * lql;
    bool bnd = (bx == 0) || (bx == (int)gridDim.x - 1);
    int S = bx << 8;
    int sAu = (S >> 1) - 1;
    int gu = S - 8;
    int gru = (S >> 1) - 4;
    int grl = S - 4;

    for (int i = tid; i < 270; i += PBLOCK) {
        const float* src; float* dst; int k, gb, len;
        if (i < 68)       { src = uprow; dst = upw; k = i;       gb = gu + 4 * k;  len = lup; }
        else if (i < 103) { src = rurow; dst = ruw; k = i - 68;  gb = gru + 4 * k; len = lu8; }
        else if (i < 138) { src = iurow; dst = iuw; k = i - 103; gb = gru + 4 * k; len = lu8; }
        else if (i < 204) { src = rlrow; dst = rlw; k = i - 138; gb = grl + 4 * k; len = lql; }
        else              { src = ilrow; dst = ilw; k = i - 204; gb = grl + 4 * k; len = lql; }
        float4 v;
        if (!bnd) v = *reinterpret_cast<const float4*>(src + gb);
        else { v.x = ldz(src, gb, len); v.y = ldz(src, gb + 1, len);
               v.z = ldz(src, gb + 2, len); v.w = ldz(src, gb + 3, len); }
        *reinterpret_cast<float4*>(dst + 4 * k) = v;
    }
    __syncthreads();

    QFilt f = load_qfilt(g0a, g0b, g1a, g1b);
    if (tid < 130) {
        float4 q = quad_i(upw, 2 * tid + 2, ruw, iuw, tid + 1, f);
        if (bnd) {
            int sp = sAu + tid;
            if (sp < 0 || sp >= lu8) q = make_float4(0.f, 0.f, 0.f, 0.f);
        }
        Ae[2 * tid] = q.x; Ae[2 * tid + 1] = q.z;
        Ao[2 * tid] = q.y; Ao[2 * tid + 1] = q.w;
    }
    __syncthreads();

    float4 res = quad_d(Ae, Ao, tid, rlw, ilw, tid + 2, f);
    reinterpret_cast<float4*>(out + (size_t)row * L)[S + tid] = res;
}

// ---- R25 final kernel: R24 with the register loads (rA/iA + rr/ii) issued
// BEFORE the stage barrier, which becomes a counted vmcnt(8) wait.
// Per-wave VMEM order (pinned by sched_barrier): stage (1-2 instr) then
// 8 reg-load instrs. s_waitcnt vmcnt(8) -> everything older than the 8 reg
// loads (i.e. the stage) has retired (in-order vmcnt), while the reg loads
// stay in flight through phases A..B (rr/ii, consumed in C by register dep)
// and A..C (rA/iA, consumed in D). The reg loads now overlap the ~900cy
// stage drain + phases A..B: >=1400cy of cover vs R24's ~500cy (which left
// phase C stalling on rr/ii — why R24 was neutral).
#define O_X4 0      // x4  [148]  slots   0..36
#define O_R3 148    // yh3r [76]  slots  37..55   (i3 at +76)
#define O_I3 224    // yh3i [76]  slots  56..74
#define O_R2 300    // yh2r [140] slots  75..109  (i2 at +140)
#define O_I2 440    // yh2i [140] slots 110..144
#define O_X3 580    // x3 values [280]
#define O_X2 860    // x2 values [528]
#define O_PT 1388   // patch [8]: tid 64's (mq0,mq1) for tid 63
#define W_TOT 1396  // dwords = 5584 B
#define NSLOT 145

static __device__ __forceinline__ void slot_map(
    int i, int v0, int u0, int t8, int t16,
    const float* x4row, const float* r3row, const float* i3row,
    const float* r2row, const float* i2row,
    const float*& src, int& gb, int& len)
{
    if (i < 37)       { src = x4row; int k = i;       gb = 2 * v0 - 8 + 4 * k; len = t8;  }
    else if (i < 56)  { src = r3row; int k = i - 37;  gb = v0 - 4 + 4 * k;     len = t16; }
    else if (i < 75)  { src = i3row; int k = i - 56;  gb = v0 - 4 + 4 * k;     len = t16; }
    else if (i < 110) { src = r2row; int k = i - 75;  gb = u0 - 4 + 4 * k;     len = t8;  }
    else              { src = i2row; int k = i - 110; gb = u0 - 4 + 4 * k;     len = t8;  }
}

__global__ void __launch_bounds__(FBLOCK) final4_async(
    const float* __restrict__ x4,                                 // T/8 per row
    const float* __restrict__ r3, const float* __restrict__ i3,   // T/16 per row
    const float* __restrict__ r2, const float* __restrict__ i2,   // T/8 per row
    const float* __restrict__ r1, const float* __restrict__ i1,   // T/4 per row
    const float* __restrict__ r0, const float* __restrict__ i0,   // T/2 per row
    float* __restrict__ out,                                      // T per row
    const float* __restrict__ g0a, const float* __restrict__ g0b,
    const float* __restrict__ g1a, const float* __restrict__ g1b,
    const float* __restrict__ g0o, const float* __restrict__ g1o,
    int T_)
{
    const float S2 = 1.4142135623730951f;
    __shared__ __align__(16) float W[W_TOT];

    int row = blockIdx.y, tid = threadIdx.x, bx = blockIdx.x;
    int t2 = T_ >> 1, t4 = T_ >> 2, t8 = T_ >> 3, t16 = T_ >> 4;
    int s0 = bx << 8, u0 = bx << 7, v0 = bx << 6, h0 = bx << 9;
    const float* x4row = x4 + (size_t)row * t8;
    const float* r3row = r3 + (size_t)row * t16;
    const float* i3row = i3 + (size_t)row * t16;
    const float* r2row = r2 + (size_t)row * t8;
    const float* i2row = i2 + (size_t)row * t8;
    const float* r1row = r1 + (size_t)row * t4;
    const float* i1row = i1 + (size_t)row * t4;
    const float* r0row = r0 + (size_t)row * t2;
    const float* i0row = i0 + (size_t)row * t2;
    bool bnd = (bx == 0) || (bx == (int)gridDim.x - 1);

    float rA[6], iA[6];   // epilogue r0/i0 windows (consumed in phase D)
    float rr[8], ii[8];   // yh1 windows (consumed in phase C)

    if (!bnd) {
        // ---- 1) stage: 145 float4 slots, direct HBM -> LDS ----
        {
            int i = tid;
            const float* src; int gb, len;
            slot_map(i, v0, u0, t8, t16, x4row, r3row, i3row, r2row, i2row,
                     src, gb, len);
            __builtin_amdgcn_global_load_lds(AS1C(src + gb), AS3(W + 4 * i), 16, 0, 0);
        }
        if (tid < NSLOT - FBLOCK) {   // 17 tail slots (wave0 only)
            int i = tid + FBLOCK;
            const float* src; int gb, len;
            slot_map(i, v0, u0, t8, t16, x4row, r3row, i3row, r2row, i2row,
                     src, gb, len);
            __builtin_amdgcn_global_load_lds(AS1C(src + gb), AS3(W + 4 * i), 16, 0, 0);
        }
        __builtin_amdgcn_sched_barrier(0);

        // ---- 2) register loads: exactly 8 VMEM instrs per wave ----
        {
            int u0e = h0 + 4 * tid - 1;
            float4 va = *reinterpret_cast<const float4*>(r0row + u0e);
            float2 va2 = *reinterpret_cast<const float2*>(r0row + u0e + 4);
            float4 vb = *reinterpret_cast<const float4*>(i0row + u0e);
            float2 vb2 = *reinterpret_cast<const float2*>(i0row + u0e + 4);
            rA[0] = va.x; rA[1] = va.y; rA[2] = va.z; rA[3] = va.w;
            rA[4] = va2.x; rA[5] = va2.y;
            iA[0] = vb.x; iA[1] = vb.y; iA[2] = vb.z; iA[3] = vb.w;
            iA[4] = vb2.x; iA[5] = vb2.y;
        }
        {
            int g1 = s0 + 2 * tid - 3;
            float4 a0 = *reinterpret_cast<const float4*>(r1row + g1);
            float4 a1 = *reinterpret_cast<const float4*>(r1row + g1 + 4);
            float4 b0 = *reinterpret_cast<const float4*>(i1row + g1);
            float4 b1 = *reinterpret_cast<const float4*>(i1row + g1 + 4);
            rr[0] = a0.x; rr[1] = a0.y; rr[2] = a0.z; rr[3] = a0.w;
            rr[4] = a1.x; rr[5] = a1.y; rr[6] = a1.z; rr[7] = a1.w;
            ii[0] = b0.x; ii[1] = b0.y; ii[2] = b0.z; ii[3] = b0.w;
            ii[4] = b1.x; ii[5] = b1.y; ii[6] = b1.z; ii[7] = b1.w;
        }
        __builtin_amdgcn_sched_barrier(0);

        // ---- 3) counted stage barrier: drain stage, keep reg loads live ----
        asm volatile("s_waitcnt vmcnt(8) lgkmcnt(0)" ::: "memory");
        __builtin_amdgcn_s_barrier();
    } else {
        // ---- boundary path (2 blocks per row): register stage, full drain ----
#pragma unroll
        for (int it = 0; it < 2; ++it) {
            int i = tid + FBLOCK * it;
            if (i < NSLOT) {
                const float* src; int gb, len;
                slot_map(i, v0, u0, t8, t16, x4row, r3row, i3row, r2row, i2row,
                         src, gb, len);
                float4 v;
                v.x = ldz(src, gb, len);     v.y = ldz(src, gb + 1, len);
                v.z = ldz(src, gb + 2, len); v.w = ldz(src, gb + 3, len);
                *reinterpret_cast<float4*>(W + 4 * i) = v;
            }
        }
        {
            int u0e = h0 + 4 * tid - 1;
#pragma unroll
            for (int e = 0; e < 6; ++e) {
                rA[e] = ldz(r0row, u0e + e, t2);
                iA[e] = ldz(i0row, u0e + e, t2);
            }
        }
        {
            int g1 = s0 + 2 * tid - 3;
#pragma unroll
            for (int j = 0; j < 8; ++j) {
                rr[j] = ldz(r1row, g1 + j, t4);
                ii[j] = ldz(i1row, g1 + j, t4);
            }
        }
        BAR_FULL();
    }

    QFiltP f = load_qfiltp(g0a, g0b, g1a, g1b);
    float g0r[7], g1r[5];
#pragma unroll
    for (int j = 0; j < 7; ++j) g0r[j] = g0o[j];
#pragma unroll
    for (int j = 0; j < 5; ++j) g1r[j] = S2 * g1o[j];

    // ---- phase A: 69 x3-quads. quad v = v0-2+k. ----
    if (tid < 69) {
        int k = tid;
        float4 q = quad_p(W, O_X4 + 2 * k, O_R3 + k, 76, f);
        if (bnd) {
            int v = v0 - 2 + k;
            if (v < 0 || v >= t16) q = make_float4(0.f, 0.f, 0.f, 0.f);
        }
        *reinterpret_cast<float4*>(W + O_X3 + 4 * k) = q;
    }
    BAR_LGKM();

    // ---- phase B: 132 x2-quads. quad u = u0-2+k; k = tid and tid+128 (<4). ----
    {
        int k = tid;
        float4 q = quad_p(W, O_X3 + 2 * k, O_R2 + k, 140, f);
        if (bnd) {
            int u = u0 - 2 + k;
            if (u < 0 || u >= t8) q = make_float4(0.f, 0.f, 0.f, 0.f);
        }
        *reinterpret_cast<float4*>(W + O_X2 + 4 * k) = q;
        if (tid < 4) {
            int k2 = tid + FBLOCK;
            q = quad_p(W, O_X3 + 2 * k2, O_R2 + k2, 140, f);
            if (bnd) {
                int u = u0 - 2 + k2;
                if (u < 0 || u >= t8) q = make_float4(0.f, 0.f, 0.f, 0.f);
            }
            *reinterpret_cast<float4*>(W + O_X2 + 4 * k2) = q;
        }
    }
    BAR_LGKM();

    // ---- phase C: x1 quads 2t, 2t+1 per thread, r/i from REGISTERS. ----
    float4 mq0, mq1;
    {
        int l = 2 * tid;
        mq0 = quad_r(W, O_X2 + 2 * l + 2, rr, ii, 0, f);
        mq1 = quad_r(W, O_X2 + 2 * l + 4, rr, ii, 1, f);
        if (bnd) {
            int s = s0 - 1 + l;
            if (s < 0 || s >= t4)         mq0 = make_float4(0.f, 0.f, 0.f, 0.f);
            if (s + 1 < 0 || s + 1 >= t4) mq1 = make_float4(0.f, 0.f, 0.f, 0.f);
        }
        if (tid == 64) {   // seam: tid 63 needs this pair (cross-wave)
            *reinterpret_cast<float4*>(W + O_PT)     = mq0;
            *reinterpret_cast<float4*>(W + O_PT + 4) = mq1;
        }
    }
    // Wave-local neighbor exchange:
    float4 nq0 = shfl_down4(mq0);
    float4 nq1 = shfl_down4(mq1);
    BAR_LGKM();   // patch visibility across waves

    // Seam fixups:
    if (tid == 63) {   // needs tid 64's pair (cross-wave patch)
        nq0 = *reinterpret_cast<const float4*>(W + O_PT);
        nq1 = *reinterpret_cast<const float4*>(W + O_PT + 4);
    }
    if (tid == 127) {  // computes extra quads 256,257 itself (off=2,3)
        float4 q0 = quad_r(W, O_X2 + 2 * 256 + 2, rr, ii, 2, f);
        float4 q1 = quad_r(W, O_X2 + 2 * 257 + 2, rr, ii, 3, f);
        if (bnd) {
            int s = s0 - 1 + 256;
            if (s < 0 || s >= t4)         q0 = make_float4(0.f, 0.f, 0.f, 0.f);
            if (s + 1 < 0 || s + 1 >= t4) q1 = make_float4(0.f, 0.f, 0.f, 0.f);
        }
        nq0 = q0; nq1 = q1;
    }

    // ---- phase D: 8 outputs. w[d] = x1[n0-4+8*tid+d] (quads 2t..2t+3). ----
    float w[16];
    *reinterpret_cast<float4*>(&w[0])  = mq0;
    *reinterpret_cast<float4*>(&w[4])  = mq1;
    *reinterpret_cast<float4*>(&w[8])  = nq0;
    *reinterpret_cast<float4*>(&w[12]) = nq1;

    float o[8];
#pragma unroll
    for (int p = 0; p < 8; ++p) {
        float acc = 0.f;
#pragma unroll
        for (int j = 0; j < 7; ++j)          // x1[n+3-j] -> w[p+7-j]
            acc = fmaf(g0r[j], w[p + 7 - j], acc);
#pragma unroll
        for (int j = 0; j < 5; ++j) {        // hi0[n+2-j] -> e = p+4-j
            int e = p + 4 - j;
            float v = (e & 1) ? iA[e >> 1] : rA[e >> 1];
            acc = fmaf(g1r[j], v, acc);
        }
        o[p] = acc;
    }
    float4* op = reinterpret_cast<float4*>(out + (size_t)row * T_) + s0 + 2 * tid;
    op[0] = make_float4(o[0], o[1], o[2], o[3]);
    op[1] = make_float4(o[4], o[5], o[6], o[7]);
}

extern "C" void kernel_launch(void* const* d_in, const int* in_sizes, int n_in,
                              void* d_out, int out_size, void* d_ws, size_t ws_size,
                              hipStream_t stream)
{
    const float* yl = (const float*)d_in[0];
    const float* yhr[8]; const float* yhi[8];
    for (int j = 0; j < 8; ++j) {
        yhr[j] = (const float*)d_in[1 + 2 * j];
        yhi[j] = (const float*)d_in[2 + 2 * j];
    }
    const float* g0o = (const float*)d_in[17];
    const float* g1o = (const float*)d_in[18];
    const float* g0a = (const float*)d_in[19];
    const float* g0b = (const float*)d_in[20];
    const float* g1a = (const float*)d_in[21];
    const float* g1b = (const float*)d_in[22];

    const int BC = 32 * 4;
    const int T_ = 262144;

    // Scratch: final reads x4 while writing the FULL d_out, so x4/x6 live in ws.
    float* x4buf = (float*)d_ws;
    float* x6buf = (float*)((char*)d_ws + ((size_t)32 << 20));

    // K76: yl + yh7 + yh6 -> x6 (L = 8192)
    {
        dim3 grid(8192 / 1024, BC);
        pair_lvl<<<grid, PBLOCK, 0, stream>>>(
            yl, yhr[7], yhi[7], yhr[6], yhi[6], x6buf,
            g0a, g0b, g1a, g1b, 8192);
    }
    // K54: x6 + yh5 + yh4 -> x4 (L = 32768)
    {
        dim3 grid(32768 / 1024, BC);
        pair_lvl<<<grid, PBLOCK, 0, stream>>>(
            x6buf, yhr[5], yhi[5], yhr[4], yhi[4], x4buf,
            g0a, g0b, g1a, g1b, 32768);
    }
    // final4_async: x4 + yh3..yh0 -> out. FT=1024, 128T, 8 outputs/thread,
    // yh1+epilogue register-resident with pre-barrier issue + counted vmcnt.
    dim3 grid(T_ / FT, BC);
    final4_async<<<grid, FBLOCK, 0, stream>>>(
        x4buf, yhr[3], yhi[3], yhr[2], yhi[2], yhr[1], yhi[1],
        yhr[0], yhi[0], (float*)d_out,
        g0a, g0b, g1a, g1b, g0o, g1o, T_);
}